// Round 7
// baseline (1288.623 us; speedup 1.0000x reference)
//
#include <hip/hip_runtime.h>

// ---------------------------------------------------------------------------
// TransMIL forward. Round 15: fattn templated on CONV — S3 gets the lean
// round-12 body (no Cv/wsm/setprio, 62.5KB LDS); S1 keeps the fused 33-tap
// resconv but with transposed conflict-free Cv[96][76] window (lanes stride
// 2B over ch, q8 groups at disjoint bank offsets {0,24,16,8}). setprio
// removed (m190: hurts barrier-synced multi-wave kernels).
// B=1, N=16384, IN=1024, C=512, heads=8, dh=64, NT=16385, NP=16640,
// landmarks M=256, l=65, pinv iters=6 (hi/lo bf16 MFMA), res conv k=33.
// ---------------------------------------------------------------------------

#define NT 16385
#define NP 16640
#define PAD 255
#define CDIM 512
#define HEADS 8
#define DH 64
#define LM 256
#define LSEG 65

typedef unsigned short u16;
typedef unsigned int u32;
typedef __attribute__((ext_vector_type(8))) short bf16x8;
typedef __attribute__((ext_vector_type(4))) float f32x4;

__device__ __forceinline__ u16 f2b(float f){
  u32 u = __float_as_uint(f);
  u32 r = (u + 0x7FFFu + ((u >> 16) & 1u)) >> 16;
  return (u16)r;
}
__device__ __forceinline__ float b2f(u16 h){ return __uint_as_float(((u32)h) << 16); }

// async global->LDS, 16 B per lane; lds dest = wave-uniform base + lane*16
__device__ __forceinline__ void gload16(const u16* g, u16* l){
  __builtin_amdgcn_global_load_lds(
      (const __attribute__((address_space(1))) u32*)g,
      (__attribute__((address_space(3))) u32*)l, 16, 0, 0);
}

// bijective XCD swizzle (m204): orig dispatch id -> contiguous-per-XCD work id
__device__ __forceinline__ int xcd_swz(int orig, int nwg){
  int qn = nwg >> 3, rn = nwg & 7;
  int xcd = orig & 7, sid = orig >> 3;
  return (xcd < rn ? xcd * (qn + 1) : rn * (qn + 1) + (xcd - rn) * qn) + sid;
}

// ---------------- reductions ----------------
__device__ __forceinline__ float wredSum(float v){
#pragma unroll
  for (int o = 32; o > 0; o >>= 1) v += __shfl_xor(v, o, 64);
  return v;
}
__device__ __forceinline__ float wredMax(float v){
#pragma unroll
  for (int o = 32; o > 0; o >>= 1) v = fmaxf(v, __shfl_xor(v, o, 64));
  return v;
}
__device__ __forceinline__ float bredSum(float v, float* sm){
  v = wredSum(v);
  int w = threadIdx.x >> 6, l = threadIdx.x & 63;
  __syncthreads();
  if (l == 0) sm[w] = v;
  __syncthreads();
  return sm[0] + sm[1] + sm[2] + sm[3];
}
__device__ __forceinline__ float bredMax(float v, float* sm){
  v = wredMax(v);
  int w = threadIdx.x >> 6, l = threadIdx.x & 63;
  __syncthreads();
  if (l == 0) sm[w] = v;
  __syncthreads();
  return fmaxf(fmaxf(sm[0], sm[1]), fmaxf(sm[2], sm[3]));
}

// ---------------- utility ----------------
__global__ __launch_bounds__(256) void copy_cls_k(const float* __restrict__ cls,
                                                  float* __restrict__ h){
  h[threadIdx.x] = cls[threadIdx.x];
  h[threadIdx.x + 256] = cls[threadIdx.x + 256];
}
__global__ __launch_bounds__(256) void cvtbf_k(const float* __restrict__ in,
                                               u16* __restrict__ out, long long n){
  long long i = ((long long)blockIdx.x * 256 + threadIdx.x) * 4;
  long long stride = (long long)gridDim.x * 256 * 4;
  for (; i < n; i += stride){
    float4 v = *(const float4*)(in + i);
    out[i]     = f2b(v.x);
    out[i + 1] = f2b(v.y);
    out[i + 2] = f2b(v.z);
    out[i + 3] = f2b(v.w);
  }
}
// f32 [R][ldin] -> bf16 transposed [C][ldout]
__global__ __launch_bounds__(256) void tcbf_k(const float* __restrict__ in,
    u16* __restrict__ out, int R, int C, int ldin, int ldout,
    long long sIn, long long sOut){
  __shared__ float t[32][33];
  in += (long long)blockIdx.z * sIn; out += (long long)blockIdx.z * sOut;
  int c0 = blockIdx.x * 32, r0 = blockIdx.y * 32;
  int x = threadIdx.x & 31, y = threadIdx.x >> 5;
  for (int yy = y; yy < 32; yy += 8){
    int r = r0 + yy, c = c0 + x;
    if (r < R && c < C) t[yy][x] = in[(long long)r * ldin + c];
  }
  __syncthreads();
  for (int yy = y; yy < 32; yy += 8){
    int c = c0 + yy, r = r0 + x;
    if (c < C && r < R) out[(long long)c * ldout + r] = f2b(t[x][yy]);
  }
}

// ---------------- bf16 MFMA GEMM (m97-style): C = alpha*A@B^T (+bias)(/rowdiv)
#define GB_STOREBF 1
#define GB_RELU    2
#define GB_ACCUM   4
#define GB_ATOMIC  8
#define GB_QSCALE  16   /* multiply cols < 512 by 0.125 (q pre-scale, exact) */
#define GB_SWZ     32   /* XCD-aware block swizzle */

template<int DBUF>
__global__ __launch_bounds__(256) void gemmbf_k(
    const u16* __restrict__ A, const u16* __restrict__ B, void* __restrict__ Cv,
    int M, int N, int K, int lda, int ldb, int ldc,
    long long sA, long long sB, long long sC,
    const float* __restrict__ bias, const float* __restrict__ rowdiv, int sRow,
    float alpha, int flags, int ksplit, u16* __restrict__ vt)
{
  __shared__ __align__(16) u16 sh[DBUF ? 32768 : 16384];   // 64 / 32 KB
  int zb = blockIdx.z / ksplit;
  int ks = blockIdx.z - zb * ksplit;
  A += (long long)zb * sA; B += (long long)zb * sB;
  float* Cf = (float*)Cv + (long long)zb * sC;
  u16*   Ch = (u16*)Cv + (long long)zb * sC;
  int klen = K / ksplit;
  int kbeg = ks * klen, kend = kbeg + klen;
  int tid = threadIdx.x;
  int w = tid >> 6, l = tid & 63;
  int row0, col0;
  if (flags & GB_SWZ){
    int gx = gridDim.x;
    int swz = xcd_swz(blockIdx.y * gx + blockIdx.x, gx * gridDim.y);
    row0 = (swz / gx) * 128; col0 = (swz % gx) * 128;
  } else {
    row0 = blockIdx.y * 128; col0 = blockIdx.x * 128;
  }
  int r8 = l >> 3;
  int csrc = ((l & 7) ^ r8) * 8;
  f32x4 acc[2][8];
#pragma unroll
  for (int i = 0; i < 2; i++)
#pragma unroll
    for (int j = 0; j < 8; j++) acc[i][j] = (f32x4){0.f, 0.f, 0.f, 0.f};

  int mrow = l & 15, q8 = l >> 4;

  auto STAGE = [&](int buf, int k0){
    u16* Asb = sh + buf * 16384;
    u16* Bsb = Asb + 8192;
#pragma unroll
    for (int c = 0; c < 4; c++){
      int r = w * 32 + c * 8;
      int gm = row0 + r + r8; if (gm >= M) gm = M - 1;
      gload16(A + (long long)gm * lda + k0 + csrc, &Asb[r * 64]);
      int gn = col0 + r + r8; if (gn >= N) gn = N - 1;
      gload16(B + (long long)gn * ldb + k0 + csrc, &Bsb[r * 64]);
    }
  };
  auto COMPUTE = [&](int buf){
    const u16* Asb = sh + buf * 16384;
    const u16* Bsb = Asb + 8192;
#pragma unroll
    for (int ks2 = 0; ks2 < 2; ks2++){
      int kc = ks2 * 4 + q8;
      bf16x8 af[2], bfr[8];
#pragma unroll
      for (int i = 0; i < 2; i++){
        int r = w * 32 + i * 16 + mrow;
        af[i] = *(const bf16x8*)&Asb[r * 64 + ((kc ^ (r & 7)) * 8)];
      }
#pragma unroll
      for (int j = 0; j < 8; j++){
        int r = j * 16 + mrow;
        bfr[j] = *(const bf16x8*)&Bsb[r * 64 + ((kc ^ (r & 7)) * 8)];
      }
#pragma unroll
      for (int i = 0; i < 2; i++)
#pragma unroll
        for (int j = 0; j < 8; j++)
          acc[i][j] = __builtin_amdgcn_mfma_f32_16x16x32_bf16(af[i], bfr[j], acc[i][j], 0, 0, 0);
    }
  };

  if constexpr (DBUF){
    STAGE(0, kbeg);
    __syncthreads();
    int cur = 0;
    for (int k0 = kbeg; k0 < kend; k0 += 64){
      if (k0 + 64 < kend) STAGE(cur ^ 1, k0 + 64);
      COMPUTE(cur);
      __syncthreads();
      cur ^= 1;
    }
  } else {
    for (int k0 = kbeg; k0 < kend; k0 += 64){
      STAGE(0, k0);
      __syncthreads();
      COMPUTE(0);
      __syncthreads();
    }
  }

  if (flags & GB_STOREBF){
    // v column-blocks (col0>=1024 with vt) are only consumed via vT -> skip
    // the row-major store entirely for them (block-uniform branch).
    if (!(vt && col0 >= 1024)){
#pragma unroll
      for (int p = 0; p < 2; p++){
        __syncthreads();
#pragma unroll
        for (int i = 0; i < 2; i++)
#pragma unroll
          for (int r = 0; r < 4; r++){
            int lrow = w * 32 + i * 16 + q8 * 4 + r;
            int gm = row0 + lrow;
            float rd = rowdiv ? rowdiv[(long long)zb * sRow + gm] : 1.f;
#pragma unroll
            for (int jj = 0; jj < 4; jj++){
              int j = p * 4 + jj;
              int gn = col0 + j * 16 + mrow;
              float v = alpha * acc[i][j][r];
              if ((flags & GB_QSCALE) && gn < 512) v *= 0.125f;
              if (rowdiv) v /= rd;
              if (bias) v += bias[gn];
              if (flags & GB_RELU) v = fmaxf(v, 0.f);
              sh[lrow * 72 + (j * 16 + mrow - p * 64)] = f2b(v);
            }
          }
        __syncthreads();
#pragma unroll
        for (int it = 0; it < 4; it++){
          int cidx = tid + it * 256;
          int rr = cidx >> 3, c8 = (cidx & 7) * 8;
          int gm = row0 + rr;
          if (gm < M)
            *(uint4*)(Ch + (long long)gm * ldc + col0 + p * 64 + c8) =
                *(const uint4*)&sh[rr * 72 + c8];
        }
      }
    }
    // fused vT output for v column-blocks: vT[(gn-1024)][gm], ld NP
    if (vt && col0 >= 1024){
      int gc0 = col0 - 1024;
#pragma unroll
      for (int p = 0; p < 2; p++){
        __syncthreads();
#pragma unroll
        for (int i = 0; i < 2; i++)
#pragma unroll
          for (int r = 0; r < 4; r++){
            int lrow = w * 32 + i * 16 + q8 * 4 + r;
#pragma unroll
            for (int jj = 0; jj < 4; jj++){
              int j = p * 4 + jj;
              int lcol = j * 16 + mrow - p * 64;
              sh[lcol * 136 + lrow] = f2b(alpha * acc[i][j][r]);
            }
          }
        __syncthreads();
#pragma unroll
        for (int it = 0; it < 4; it++){
          int cidx = tid + it * 256;
          int cc = cidx >> 4, rc = (cidx & 15) * 8;
          *(uint4*)(vt + (long long)(gc0 + p * 64 + cc) * NP + row0 + rc) =
              *(const uint4*)&sh[cc * 136 + rc];
        }
      }
    }
    return;
  }

  if constexpr (DBUF){
    if (!(flags & GB_ATOMIC)){
      float* shf = (float*)sh;
#pragma unroll
      for (int p = 0; p < 2; p++){
        __syncthreads();
#pragma unroll
        for (int i = 0; i < 2; i++)
#pragma unroll
          for (int r = 0; r < 4; r++){
            int lrow = w * 32 + i * 16 + q8 * 4 + r;
            int gm = row0 + lrow;
            int gmc = (gm < M) ? gm : M - 1;
            float rd = rowdiv ? rowdiv[(long long)zb * sRow + gmc] : 1.f;
#pragma unroll
            for (int jj = 0; jj < 4; jj++){
              int j = p * 4 + jj;
              int gn = col0 + j * 16 + mrow;
              float v = alpha * acc[i][j][r];
              if ((flags & GB_QSCALE) && gn < 512) v *= 0.125f;
              if (rowdiv) v /= rd;
              if (bias) v += bias[gn];
              if (flags & GB_RELU) v = fmaxf(v, 0.f);
              shf[lrow * 68 + (j * 16 + mrow - p * 64)] = v;
            }
          }
        __syncthreads();
#pragma unroll
        for (int it = 0; it < 8; it++){
          int cidx = tid + it * 256;
          int rr = cidx >> 4, c4 = (cidx & 15) * 4;
          int gm = row0 + rr;
          if (gm >= M) continue;
          int gn = col0 + p * 64 + c4;
          if (gn + 3 < N){
            float4* dst = (float4*)(Cf + (long long)gm * ldc + gn);
            float4 vv = *(const float4*)&shf[rr * 68 + c4];
            if (flags & GB_ACCUM){
              float4 o = *dst;
              vv.x += o.x; vv.y += o.y; vv.z += o.z; vv.w += o.w;
            }
            *dst = vv;
          } else {
            for (int e = 0; e < 4; e++){
              if (gn + e >= N) break;
              float v = shf[rr * 68 + c4 + e];
              if (flags & GB_ACCUM) Cf[(long long)gm * ldc + gn + e] += v;
              else Cf[(long long)gm * ldc + gn + e] = v;
            }
          }
        }
      }
      return;
    }
  }

#pragma unroll
  for (int i = 0; i < 2; i++){
#pragma unroll
    for (int r = 0; r < 4; r++){
      int gm = row0 + w * 32 + i * 16 + q8 * 4 + r;
      if (gm >= M) continue;
      float rd = rowdiv ? rowdiv[(long long)zb * sRow + gm] : 1.f;
#pragma unroll
      for (int j = 0; j < 8; j++){
        int gn = col0 + j * 16 + mrow;
        if (gn >= N) continue;
        float v = alpha * acc[i][j][r];
        if ((flags & GB_QSCALE) && gn < 512) v *= 0.125f;
        if (rowdiv) v /= rd;
        if (bias) v += bias[gn];
        if (flags & GB_RELU) v = fmaxf(v, 0.f);
        long long ci = (long long)gm * ldc + gn;
        if (flags & GB_ATOMIC) atomicAdd(&Cf[ci], v);
        else if (flags & GB_ACCUM) Cf[ci] += v;
        else Cf[ci] = v;
      }
    }
  }
}

// ---------------- hi/lo bf16 MFMA pinv stage (64x64 tiles, K-dbuf) ---------
__device__ __forceinline__ void pinv_core(
    u16* lds, int cb, int rb, int head,
    const u16* __restrict__ Ah, const u16* __restrict__ Al,
    const u16* __restrict__ BTh, const u16* __restrict__ BTl,
    u16* __restrict__ Chh, u16* __restrict__ Cll,
    u16* __restrict__ CTh, u16* __restrict__ CTl,
    float* __restrict__ Cf,
    const u16* __restrict__ Avh, const u16* __restrict__ Avl,
    float dterm, float sterm, float eterm)
{
  long long off = (long long)head << 16;
  int tid = threadIdx.x, w = tid >> 6, l = tid & 63;
  int row0 = rb * 64, col0 = cb * 64;
  int r8 = l >> 3;
  int csrc = ((l & 7) ^ r8) * 8;
  int mrow = l & 15, q8 = l >> 4;
  f32x4 acc[4];
#pragma unroll
  for (int j = 0; j < 4; j++) acc[j] = (f32x4){0.f, 0.f, 0.f, 0.f};

  auto STAGE = [&](int buf, int k0){
    u16* Ash = lds + buf * 16384;
    u16* Asl = Ash + 4096;
    u16* Bsh = Ash + 8192;
    u16* Bsl = Ash + 12288;
#pragma unroll
    for (int c = 0; c < 2; c++){
      int r = w * 16 + c * 8;
      long long ga = off + (long long)(row0 + r + r8) * 256 + k0 + csrc;
      gload16(Ah + ga, &Ash[r * 64]);
      gload16(Al + ga, &Asl[r * 64]);
      long long gb = off + (long long)(col0 + r + r8) * 256 + k0 + csrc;
      gload16(BTh + gb, &Bsh[r * 64]);
      gload16(BTl + gb, &Bsl[r * 64]);
    }
  };
  auto COMPUTE = [&](int buf){
    const u16* Ash = lds + buf * 16384;
    const u16* Asl = Ash + 4096;
    const u16* Bsh = Ash + 8192;
    const u16* Bsl = Ash + 12288;
#pragma unroll
    for (int ks2 = 0; ks2 < 2; ks2++){
      int kc = ks2 * 4 + q8;
      bf16x8 ah, al, bh[4], bl[4];
      {
        int r = w * 16 + mrow;
        int idx = r * 64 + ((kc ^ (r & 7)) * 8);
        ah = *(const bf16x8*)&Ash[idx];
        al = *(const bf16x8*)&Asl[idx];
      }
#pragma unroll
      for (int j = 0; j < 4; j++){
        int r = j * 16 + mrow;
        int idx = r * 64 + ((kc ^ (r & 7)) * 8);
        bh[j] = *(const bf16x8*)&Bsh[idx];
        bl[j] = *(const bf16x8*)&Bsl[idx];
      }
#pragma unroll
      for (int j = 0; j < 4; j++){
        acc[j] = __builtin_amdgcn_mfma_f32_16x16x32_bf16(ah, bh[j], acc[j], 0, 0, 0);
        acc[j] = __builtin_amdgcn_mfma_f32_16x16x32_bf16(ah, bl[j], acc[j], 0, 0, 0);
        acc[j] = __builtin_amdgcn_mfma_f32_16x16x32_bf16(al, bh[j], acc[j], 0, 0, 0);
      }
    }
  };

  STAGE(0, 0);
  __syncthreads();
  int cur = 0;
  for (int k0 = 0; k0 < 256; k0 += 64){
    if (k0 + 64 < 256) STAGE(cur ^ 1, k0 + 64);
    COMPUTE(cur);
    __syncthreads();
    cur ^= 1;
  }

#pragma unroll
  for (int r = 0; r < 4; r++){
    int gm = row0 + w * 16 + q8 * 4 + r;
#pragma unroll
    for (int j = 0; j < 4; j++){
      int gn = col0 + j * 16 + mrow;
      float v = sterm * acc[j][r];
      if (Avh){
        long long ai = off + (long long)gm * 256 + gn;
        v += eterm * (b2f(Avh[ai]) + b2f(Avl[ai]));
      }
      if (gm == gn) v += dterm;
      acc[j][r] = v;
      long long ci = off + (long long)gm * 256 + gn;
      if (Cf) Cf[ci] = v;
      if (Chh){
        u16 hi = f2b(v);
        Chh[ci] = hi;
        Cll[ci] = f2b(v - b2f(hi));
      }
    }
  }
  if (CTh){
#pragma unroll
    for (int pass = 0; pass < 2; pass++){
      __syncthreads();
#pragma unroll
      for (int r = 0; r < 4; r++){
        int lm = w * 16 + q8 * 4 + r;
#pragma unroll
        for (int j = 0; j < 4; j++){
          int ln = j * 16 + mrow;
          float v = acc[j][r];
          u16 hi = f2b(v);
          lds[ln * 72 + lm] = (pass == 0) ? hi : f2b(v - b2f(hi));
        }
      }
      __syncthreads();
      u16* dst = (pass == 0) ? CTh : CTl;
#pragma unroll
      for (int it = 0; it < 2; it++){
        int cidx = tid + it * 256;
        int rr = cidx >> 3;
        int cc = (cidx & 7) * 8;
        *(uint4*)(dst + off + (long long)(col0 + rr) * 256 + row0 + cc) =
            *(const uint4*)&lds[rr * 72 + cc];
      }
    }
  }
}

__global__ __launch_bounds__(256) void pinvh_k(
    const u16* __restrict__ Ah, const u16* __restrict__ Al,
    const u16* __restrict__ BTh, const u16* __restrict__ BTl,
    u16* __restrict__ Chh, u16* __restrict__ Cll,
    u16* __restrict__ CTh, u16* __restrict__ CTl,
    float* __restrict__ Cf,
    const u16* __restrict__ Avh, const u16* __restrict__ Avl,
    float dterm, float sterm, float eterm)
{
  __shared__ __align__(16) u16 lds[32768];   // 64 KB (2 x 32 KB buffers)
  pinv_core(lds, blockIdx.x, blockIdx.y, blockIdx.z,
            Ah, Al, BTh, BTl, Chh, Cll, CTh, CTl, Cf, Avh, Avl,
            dterm, sterm, eterm);
}
__global__ __launch_bounds__(256) void pinv2_k(
    const u16* __restrict__ azh, const u16* __restrict__ azl,
    const u16* __restrict__ azTh, const u16* __restrict__ azTl,
    const u16* __restrict__ zh, const u16* __restrict__ zl,
    u16* __restrict__ tATh, u16* __restrict__ tATl,
    u16* __restrict__ zah, u16* __restrict__ zal)
{
  __shared__ __align__(16) u16 lds[32768];
  int head = blockIdx.z & 7;
  if (blockIdx.z < 8)
    pinv_core(lds, blockIdx.x, blockIdx.y, head, azh, azl, azTh, azTl,
              nullptr, nullptr, tATh, tATl, nullptr, azh, azl, 15.f, 1.f, -7.f);
  else
    pinv_core(lds, blockIdx.x, blockIdx.y, head, zh, zl, azTh, azTl,
              zah, zal, nullptr, nullptr, nullptr, nullptr, nullptr, 0.f, 1.f, 0.f);
}

// ---------------- f32 GEMM (small: a2, Z2) ----------------
#define GF_TRANSB 1
__global__ __launch_bounds__(256) void gemm_k(
    const float* __restrict__ A, const float* __restrict__ B, float* __restrict__ C,
    int M, int N, int K, int lda, int ldb, int ldc,
    long long sA, long long sB, long long sC, float alpha, int flags)
{
  __shared__ __align__(16) float As[16][68];
  __shared__ __align__(16) float Bs[16][68];
  int zb = blockIdx.z;
  A += (long long)zb * sA; B += (long long)zb * sB; C += (long long)zb * sC;
  int tid = threadIdx.x;
  int tx = tid & 15, ty = tid >> 4;
  int row0 = blockIdx.y * 64, col0 = blockIdx.x * 64;
  float acc[4][4] = {};
  for (int k0 = 0; k0 < K; k0 += 16){
#pragma unroll
    for (int i = 0; i < 4; i++){
      int idx = tid + i * 256;
      int mm = idx >> 4, kk = idx & 15;
      int gm = row0 + mm;
      As[kk][mm] = (gm < M) ? A[(long long)gm * lda + (k0 + kk)] : 0.f;
    }
    if (!(flags & GF_TRANSB)){
#pragma unroll
      for (int i = 0; i < 4; i++){
        int idx = tid + i * 256;
        int kk = idx >> 6, nn = idx & 63;
        int gn = col0 + nn;
        Bs[kk][nn] = (gn < N) ? B[(long long)(k0 + kk) * ldb + gn] : 0.f;
      }
    } else {
#pragma unroll
      for (int i = 0; i < 4; i++){
        int idx = tid + i * 256;
        int nn = idx >> 4, kk = idx & 15;
        int gn = col0 + nn;
        Bs[kk][nn] = (gn < N) ? B[(long long)gn * ldb + (k0 + kk)] : 0.f;
      }
    }
    __syncthreads();
#pragma unroll
    for (int kk = 0; kk < 16; kk++){
      float4 av = *(const float4*)&As[kk][ty * 4];
      float4 bv = *(const float4*)&Bs[kk][tx * 4];
      float a[4] = {av.x, av.y, av.z, av.w};
      float b[4] = {bv.x, bv.y, bv.z, bv.w};
#pragma unroll
      for (int i = 0; i < 4; i++)
#pragma unroll
        for (int j = 0; j < 4; j++)
          acc[i][j] = fmaf(a[i], b[j], acc[i][j]);
    }
    __syncthreads();
  }
#pragma unroll
  for (int i = 0; i < 4; i++){
    int gm = row0 + ty * 4 + i;
    if (gm >= M) continue;
#pragma unroll
    for (int j = 0; j < 4; j++){
      int gn = col0 + tx * 4 + j;
      if (gn >= N) continue;
      C[(long long)gm * ldc + gn] = alpha * acc[i][j];
    }
  }
}

// ---------------- fused flash attention (+ compile-time fused resconv) -----
template<int CONV>
__global__ __launch_bounds__(256) void fattn_k(
    const u16* __restrict__ Qp, int ldq,
    const u16* __restrict__ Kp, int ldk,
    const u16* __restrict__ Vp, int ldv,
    long long sQh, long long sKh, long long sVh,
    int keysPerChunk,
    u16* __restrict__ outB, int ldo,
    float* __restrict__ O3, float* __restrict__ ML3, int nchunks, int qrows,
    int mode, const u16* __restrict__ vTc, const float* __restrict__ rw)
{
  __shared__ u16 Qs[64][72];
  __shared__ u16 Ks[128][72];
  __shared__ u16 Vs[64][136];
  __shared__ u16 Ps[4][16][136];
  // transposed conv window: Cv[p][ch] = vT[h*64+ch][q0-16+p]; row 76 u16
  // -> lanes stride 2B over ch (free), q8 groups at banks {0,24,16,8} (free)
  __shared__ u16 Cv[CONV ? 96 : 1][76];
  __shared__ float wsm[CONV ? 33 : 1];
  int tid = threadIdx.x;
  int w = tid >> 6, l = tid & 63;
  int mrow = l & 15, q8 = l >> 4;
  int gx = gridDim.x, gy = gridDim.y;
  int swz = xcd_swz((blockIdx.z * gy + blockIdx.y) * gx + blockIdx.x,
                    gx * gy * gridDim.z);
  int qt = swz % gx, t2 = swz / gx;
  int ch_ = t2 % gy, h = t2 / gy;
  const u16* Q = Qp + (long long)h * sQh;
  const u16* K = Kp + (long long)h * sKh;
  const u16* V = Vp + (long long)h * sVh;
  int q0 = qt * 64;
  for (int i = tid; i < 512; i += 256){
    int r = i >> 3, c = (i & 7) * 8;
    *(uint4*)&Qs[r][c] = *(const uint4*)(Q + (long long)(q0 + r) * ldq + c);
  }
  if constexpr (CONV){
    if (tid < 33) wsm[tid] = rw[h * 33 + tid];
    for (int i = tid; i < 768; i += 256){
      int ch = i & 63, seg = i >> 6;        // seg 0..11
      int row = q0 - 16 + seg * 8;
      const u16* src = vTc + (long long)(h * 64 + ch) * NP;
      u16 tmp[8];
      if (row >= 0 && row + 8 <= NP){
        *(uint4*)tmp = *(const uint4*)(src + row);
      } else {
#pragma unroll
        for (int e = 0; e < 8; e++){
          int rr2 = row + e;
          tmp[e] = (rr2 >= 0 && rr2 < NP) ? src[rr2] : (u16)0;
        }
      }
#pragma unroll
      for (int e = 0; e < 8; e++) Cv[seg * 8 + e][ch] = tmp[e];
    }
  }
  float m_st[4], l_st[4];
  f32x4 acc_o[4];
#pragma unroll
  for (int r = 0; r < 4; r++){
    m_st[r] = -3.0e38f; l_st[r] = 0.f;
    acc_o[r] = (f32x4){0.f, 0.f, 0.f, 0.f};
  }
  int kbase = ch_ * keysPerChunk;
  for (int kt = 0; kt < keysPerChunk; kt += 128){
    for (int i = tid; i < 1024; i += 256){
      int r = i >> 3, c = (i & 7) * 8;
      *(uint4*)&Ks[r][c] = *(const uint4*)(K + (long long)(kbase + kt + r) * ldk + c);
    }
    for (int i = tid; i < 1024; i += 256){
      int r = i >> 4, c = (i & 15) * 8;
      *(uint4*)&Vs[r][c] = *(const uint4*)(V + (long long)r * ldv + kbase + kt + c);
    }
    __syncthreads();
    f32x4 accs[8];
#pragma unroll
    for (int j = 0; j < 8; j++) accs[j] = (f32x4){0.f, 0.f, 0.f, 0.f};
#pragma unroll
    for (int ks2 = 0; ks2 < 2; ks2++){
      bf16x8 af = *(const bf16x8*)&Qs[w * 16 + mrow][ks2 * 32 + q8 * 8];
#pragma unroll
      for (int j = 0; j < 8; j++){
        bf16x8 bfv = *(const bf16x8*)&Ks[j * 16 + mrow][ks2 * 32 + q8 * 8];
        accs[j] = __builtin_amdgcn_mfma_f32_16x16x32_bf16(af, bfv, accs[j], 0, 0, 0);
      }
    }
#pragma unroll
    for (int r = 0; r < 4; r++){
      float tm = -3.0e38f;
#pragma unroll
      for (int j = 0; j < 8; j++) tm = fmaxf(tm, accs[j][r]);
      tm = fmaxf(tm, __shfl_xor(tm, 1, 64));
      tm = fmaxf(tm, __shfl_xor(tm, 2, 64));
      tm = fmaxf(tm, __shfl_xor(tm, 4, 64));
      tm = fmaxf(tm, __shfl_xor(tm, 8, 64));
      float mn = fmaxf(m_st[r], tm);
      float al = __expf(m_st[r] - mn);
      m_st[r] = mn;
      float rs = 0.f;
#pragma unroll
      for (int j = 0; j < 8; j++){
        float e = __expf(accs[j][r] - mn);
        accs[j][r] = e;
        rs += e;
      }
      rs += __shfl_xor(rs, 1, 64);
      rs += __shfl_xor(rs, 2, 64);
      rs += __shfl_xor(rs, 4, 64);
      rs += __shfl_xor(rs, 8, 64);
      l_st[r] = al * l_st[r] + rs;
#pragma unroll
      for (int j = 0; j < 4; j++) acc_o[j][r] *= al;
    }
#pragma unroll
    for (int j = 0; j < 8; j++)
#pragma unroll
      for (int r = 0; r < 4; r++)
        Ps[w][q8 * 4 + r][j * 16 + mrow] = f2b(accs[j][r]);
    __syncthreads();
#pragma unroll
    for (int kc = 0; kc < 4; kc++){
      bf16x8 af = *(const bf16x8*)&Ps[w][mrow][kc * 32 + q8 * 8];
#pragma unroll
      for (int j = 0; j < 4; j++){
        bf16x8 bfv = *(const bf16x8*)&Vs[j * 16 + mrow][kc * 32 + q8 * 8];
        acc_o[j] = __builtin_amdgcn_mfma_f32_16x16x32_bf16(af, bfv, acc_o[j], 0, 0, 0);
      }
    }
    __syncthreads();
  }
  if (mode == 0){
    float invr[4];
#pragma unroll
    for (int r = 0; r < 4; r++) invr[r] = 1.f / l_st[r];
#pragma unroll
    for (int j = 0; j < 4; j++){
      int ch = j * 16 + mrow;
      float conv[4] = {0.f, 0.f, 0.f, 0.f};
      if constexpr (CONV){
        int rr0 = w * 16 + q8 * 4;
        float win[36];
#pragma unroll
        for (int t = 0; t < 36; t++) win[t] = b2f(Cv[rr0 + t][ch]);
#pragma unroll
        for (int r = 0; r < 4; r++){
          float a = 0.f;
#pragma unroll
          for (int t = 0; t < 33; t++) a = fmaf(win[r + t], wsm[t], a);
          conv[r] = a;
        }
      }
#pragma unroll
      for (int r = 0; r < 4; r++){
        int grow = q0 + w * 16 + q8 * 4 + r;
        u16 o16 = f2b(acc_o[j][r] * invr[r]);
        // bit-identical to separate resconv RMW: round, add conv, round
        outB[(long long)grow * ldo + h * 64 + ch] =
            CONV ? f2b(b2f(o16) + conv[r]) : o16;
      }
    }
  } else {
#pragma unroll
    for (int r = 0; r < 4; r++){
      int row = q0 + w * 16 + q8 * 4 + r;
      long long b = ((long long)h * nchunks + ch_) * qrows + row;
#pragma unroll
      for (int j = 0; j < 4; j++)
        O3[b * 64 + j * 16 + mrow] = acc_o[j][r];
      if (mrow == 0){
        ML3[b * 2] = m_st[r];
        ML3[b * 2 + 1] = l_st[r];
      }
    }
  }
}

// combine S3 partials
__global__ __launch_bounds__(256) void comb3_k(
    const float* __restrict__ O3, const float* __restrict__ ML3,
    float* __restrict__ a3v)
{
  int h = blockIdx.y;
  int row = blockIdx.x * 4 + (threadIdx.x >> 6);
  int d = threadIdx.x & 63;
  float m = -3.0e38f;
  for (int c = 0; c < 13; c++)
    m = fmaxf(m, ML3[(((long long)h * 13 + c) * 256 + row) * 2]);
  float l = 0.f, o = 0.f;
  for (int c = 0; c < 13; c++){
    long long b = ((long long)h * 13 + c) * 256 + row;
    float wgt = __expf(ML3[b * 2] - m);
    l += wgt * ML3[b * 2 + 1];
    o += wgt * O3[b * 64 + d];
  }
  a3v[((long long)h * 256 + row) * 64 + d] = o / l;
}

// ---------------- layernorm + front-pad -> bf16 xq (NP x 512) --------------
__global__ __launch_bounds__(256) void ln_pad_k(
    const float* __restrict__ h, const float* __restrict__ g,
    const float* __restrict__ b, u16* __restrict__ out)
{
  __shared__ float sm[4];
  int row = blockIdx.x, tid = threadIdx.x;
  u16* o = out + (long long)row * CDIM;
  if (row < PAD){ o[tid] = 0; o[tid + 256] = 0; return; }
  const float* x = h + (long long)(row - PAD) * CDIM;
  float v0 = x[tid], v1 = x[tid + 256];
  float s = bredSum(v0 + v1, sm);
  float s2 = bredSum(v0 * v0 + v1 * v1, sm);
  float mean = s * (1.f / 512.f);
  float var = s2 * (1.f / 512.f) - mean * mean;
  float rstd = rsqrtf(var + 1e-5f);
  o[tid] = f2b((v0 - mean) * rstd * g[tid] + b[tid]);
  o[tid + 256] = f2b((v1 - mean) * rstd * g[tid + 256] + b[tid + 256]);
}

// ---------------- landmark means (vectorized; q pre-scaled by 0.125) -------
__global__ __launch_bounds__(256) void landmark_k(
    const u16* __restrict__ qkv, float* __restrict__ ql, float* __restrict__ kl,
    u16* __restrict__ qlh, u16* __restrict__ klh)
{
  int m = blockIdx.x * 2 + (threadIdx.x >> 7);
  int c8 = (threadIdx.x & 127) * 8;
  const u16* base = qkv + (long long)(m * LSEG) * 1536 + c8;
  float s[8] = {};
  for (int j = 0; j < LSEG; j++){
    uint4 pk = *(const uint4*)(base + (long long)j * 1536);
    const u16* pv = (const u16*)&pk;
#pragma unroll
    for (int e = 0; e < 8; e++) s[e] += b2f(pv[e]);
  }
#pragma unroll
  for (int e = 0; e < 8; e++){
    int col = c8 + e;
    float v = s[e] * (1.f / 65.f);
    int h = (col & 511) >> 6, d = col & 63;
    int idx = (h * LM + m) * DH + d;
    if (col < 512){ ql[idx] = v; qlh[idx] = f2b(v); }
    else          { kl[idx] = v; klh[idx] = f2b(v); }
  }
}

// ---------------- softmax over rows of 256 (f32 + hi/lo bf16 out) ----------
__global__ __launch_bounds__(256) void softmax256_k(float* __restrict__ S,
    u16* __restrict__ a2h, u16* __restrict__ a2l, float* __restrict__ scal)
{
  __shared__ float sm[4];
  int i = blockIdx.x, h = blockIdx.y, j = threadIdx.x;
  if (i == 0 && h == 0 && j < 2) scal[j] = 0.f;
  long long idx = ((long long)h * LM + i) * 256 + j;
  float v = S[idx];
  float m = bredMax(v, sm);
  float e = __expf(v - m);
  float s = bredSum(e, sm);
  float p = e / s;
  S[idx] = p;
  u16 hi = f2b(p);
  a2h[idx] = hi;
  a2l[idx] = f2b(p - b2f(hi));
}

// ---------------- pinv scale factors ----------------
__global__ __launch_bounds__(256) void pinv_scal_k(
    const float* __restrict__ a2, float* __restrict__ scal)
{
  __shared__ float sm[4];
  int h = blockIdx.x, i = threadIdx.x;
  const float* Ah = a2 + (long long)h * 65536;
  float rs = 0.f, cs = 0.f;
  for (int j = 0; j < 256; j++){
    rs += fabsf(Ah[i * 256 + j]);
    cs += fabsf(Ah[j * 256 + i]);
  }
  float rmax = bredMax(rs, sm);
  __syncthreads();
  float cmax = bredMax(cs, sm);
  if (i == 0){
    atomicMax((int*)&scal[0], __float_as_int(rmax));
    atomicMax((int*)&scal[1], __float_as_int(cmax));
  }
}

// z0 = a2^T * inv (hi/lo + transposed hi/lo)
__global__ __launch_bounds__(256) void z0_k(
    const float* __restrict__ a2, const float* __restrict__ scal,
    u16* __restrict__ zh, u16* __restrict__ zl,
    u16* __restrict__ zTh, u16* __restrict__ zTl)
{
  int ri = blockIdx.x, h = blockIdx.y, j = threadIdx.x;
  float inv = 1.f / (scal[0] * scal[1]);
  long long base = ((long long)h * LM + ri) * 256;
  float v = a2[base + j] * inv;
  u16 hi = f2b(v), lo = f2b(v - b2f(hi));
  zTh[base + j] = hi; zTl[base + j] = lo;
  long long tb = ((long long)h * LM + j) * 256 + ri;
  zh[tb] = hi; zl[tb] = lo;
}

// ---------------- f32 32x32 transpose ----------------
__global__ __launch_bounds__(256) void transpose_k(
    const float* __restrict__ in, float* __restrict__ out, int R, int Cc)
{
  __shared__ float t[32][33];
  int bx = blockIdx.x * 32, by = blockIdx.y * 32;
  int x = threadIdx.x & 31, y4 = threadIdx.x >> 5;
  for (int yy = y4; yy < 32; yy += 8){
    int r = by + yy, c = bx + x;
    if (r < R && c < Cc) t[yy][x] = in[(long long)r * Cc + c];
  }
  __syncthreads();
  for (int yy = y4; yy < 32; yy += 8){
    int r = bx + yy, c = by + x;
    if (r < Cc && c < R) out[(long long)r * R + c] = t[x][yy];
  }
}

// ---------------- fused PPEG (16x128 strip, register column window) --------
__global__ __launch_bounds__(256) void ppeg_k(
    const float* __restrict__ cf, float* __restrict__ yt,
    const float* __restrict__ w7, const float* __restrict__ b7,
    const float* __restrict__ w5, const float* __restrict__ b5,
    const float* __restrict__ w3, const float* __restrict__ b3)
{
  __shared__ float tile[22][136];   // rows ys-3..ys+18, cols -3..130
  __shared__ float wsh[84];
  int c = blockIdx.y;
  int ys = blockIdx.x * 16;
  int tid = threadIdx.x;
  const float* img = cf + (long long)c * 16384;
  if (tid < 49) wsh[tid] = w7[c * 49 + tid];
  else if (tid >= 64 && tid < 89) wsh[49 + tid - 64] = w5[c * 25 + (tid - 64)];
  else if (tid >= 96 && tid < 105) wsh[74 + tid - 96] = w3[c * 9 + (tid - 96)];
  else if (tid == 128) wsh[83] = b7[c] + b5[c] + b3[c];
  for (int i = tid; i < 22 * 134; i += 256){
    int yy = i / 134, xx = i - yy * 134;
    int gy = ys - 3 + yy, gx = xx - 3;
    tile[yy][xx] = (gy >= 0 && gy < 128 && gx >= 0 && gx < 128) ? img[gy * 128 + gx] : 0.f;
  }
  __syncthreads();
  int x = tid & 127;
  int yo = (tid >> 7) * 8;     // 0 or 8
  float acc[8];
#pragma unroll
  for (int i = 0; i < 8; i++) acc[i] = tile[yo + i + 3][x + 3] + wsh[83];
#pragma unroll
  for (int kx = 0; kx < 7; kx++){
    float col[14];
#pragma unroll
    for (int t = 0; t < 14; t++) col[t] = tile[yo + t][x + kx];
    float wc7[7];
#pragma unroll
    for (int ky = 0; ky < 7; ky++) wc7[ky] = wsh[ky * 7 + kx];
#pragma unroll
    for (int i = 0; i < 8; i++)
#pragma unroll
      for (int ky = 0; ky < 7; ky++)
        acc[i] = fmaf(col[i + ky], wc7[ky], acc[i]);
    if (kx >= 1 && kx <= 5){
      float wc5[5];
#pragma unroll
      for (int ky = 0; ky < 5; ky++) wc5[ky] = wsh[49 + ky * 5 + (kx - 1)];
#pragma unroll
      for (int i = 0; i < 8; i++)
#pragma unroll
        for (int ky = 0; ky < 5; ky++)
          acc[i] = fmaf(col[i + 1 + ky], wc5[ky], acc[i]);
    }
    if (kx >= 2 && kx <= 4){
      float wc3[3];
#pragma unroll
      for (int ky = 0; ky < 3; ky++) wc3[ky] = wsh[74 + ky * 3 + (kx - 2)];
#pragma unroll
      for (int i = 0; i < 8; i++)
#pragma unroll
        for (int ky = 0; ky < 3; ky++)
          acc[i] = fmaf(col[i + 2 + ky], wc3[ky], acc[i]);
    }
  }
  float* dst = yt + (long long)c * 16384 + (ys + yo) * 128 + x;
#pragma unroll
  for (int i = 0; i < 8; i++) dst[i * 128] = acc[i];
}

// ---------------- final: LN(h[0]) @ fc2 + b ----------------
__global__ __launch_bounds__(256) void final_k(
    const float* __restrict__ h, const float* __restrict__ g,
    const float* __restrict__ b, const float* __restrict__ w,
    const float* __restrict__ bias, float* __restrict__ out)
{
  __shared__ float sm[4];
  __shared__ float pj[256][4];
  int tid = threadIdx.x;
  float v0 = h[tid], v1 = h[tid + 256];
  float s = bredSum(v0 + v1, sm);
  float s2 = bredSum(v0 * v0 + v1 * v1, sm);
  float mean = s * (1.f / 512.f);
  float var = s2 * (1.f / 512.f) - mean * mean;
  float rstd = rsqrtf(var + 1e-5f);
  float n0 = (v0 - mean) * rstd * g[tid] + b[tid];
  float n1 = (v1 - mean) * rstd * g[tid + 256] + b[tid + 256];
#pragma unroll
  for (int j = 0; j < 4; j++)
    pj[tid][j] = n0 * w[tid * 4 + j] + n1 * w[(tid + 256) * 4 + j];
  __syncthreads();
  if (tid < 4){
    float acc = 0.f;
    for (int k = 0; k < 256; k++) acc += pj[k][tid];
    out[tid] = acc + bias[tid];
  }
}

// ===========================================================================
// host side
// ===========================================================================
static inline void gemmbf(hipStream_t st, const u16* A, const u16* B, void* C,
                          int M, int N, int K, int lda, int ldb, int ldc,
                          long long sA, long long sB, long long sC, int batch,
                          const float* bias, const float* rowdiv, int sRow,
                          float alpha, int flags, int ksplit, u16* vt, int dbuf)
{
  dim3 grid((N + 127) / 128, (M + 127) / 128, batch * ksplit);
  if (dbuf)
    gemmbf_k<1><<<grid, 256, 0, st>>>(A, B, C, M, N, K, lda, ldb, ldc, sA, sB, sC,
                                      bias, rowdiv, sRow, alpha, flags, ksplit, vt);
  else
    gemmbf_k<0><<<grid, 256, 0, st>>>(A, B, C, M, N, K, lda, ldb, ldc, sA, sB, sC,
                                      bias, rowdiv, sRow, alpha, flags, ksplit, vt);
}

// workspace byte offsets
#define B_H     0LL
#define B_XQ    33556480LL     /* xq; after qkv, hosts pinv hi/lo arrays (16MB) */
#define B_ATTN  50595840LL
#define B_QKV   67635200LL     /* also xb; also cf/yt for PPEG */
#define B_VT    118753280LL
#define B_O3    135792640LL
#define B_ML3   142608384LL
#define B_QL    169871360LL
#define B_KL    170395648LL
#define B_QLH   170919936LL
#define B_KLH   171182080LL
#define B_A2    171444224LL
#define B_PV2   173541376LL    /* zah(1M), zal(1M), zf f32(2M) */
#define B_A3V   184027136LL
#define B_Z2    184551424LL
#define B_Z2T   185075712LL
#define B_SCAL  185604096LL
#define B_W1T   185604352LL
#define B_WQT   186652928LL
#define B_WOT   188225792LL
#define WS_REQ  188750080LL
#define MB1     1048576LL

extern "C" void kernel_launch(void* const* d_in, const int* in_sizes, int n_in,
                              void* d_out, int out_size, void* d_ws, size_t ws_size,
                              hipStream_t stream)
{
  (void)in_sizes; (void)n_in; (void)out_size;
  if (ws_size < (size_t)WS_REQ) return;

  const float* x      = (const float*)d_in[0];
  const float* fc1_w  = (const float*)d_in[1];
  const float* fc1_b  = (const float*)d_in[2];
  const float* cls    = (const float*)d_in[3];
  const float* l_ng[2]  = {(const float*)d_in[4],  (const float*)d_in[10]};
  const float* l_nb[2]  = {(const float*)d_in[5],  (const float*)d_in[11]};
  const float* l_qkv[2] = {(const float*)d_in[6],  (const float*)d_in[12]};
  const float* l_ow[2]  = {(const float*)d_in[7],  (const float*)d_in[13]};
  const float* l_ob[2]  = {(const float*)d_in[8],  (const float*)d_in[14]};
  const float* l_rw[2]  = {(const float*)d_in[9],  (const float*)d_in[15]};
  const float* w7 = (const float*)d_in[16];
  const float* b7 = (const float*)d_in[17];
  const float* w5 = (const float*)d_in[18];
  const float* b5 = (const float*)d_in[19];
  const float* w3 = (const float*)d_in[20];
  const float* b3 = (const float*)d_in[21];
  const float* norm_g = (const float*)d_in[22];
  const float* norm_b = (const float*)d_in[23];
  const float* fc2_w  = (const float*)d_in[24];
  const float* fc2_b  = (const float*)d_in[25];
  float* out = (float*)d_out;

  char* WB = (char*)d_ws;
  float* h    = (float*)(WB + B_H);
  u16*   xq   = (u16*)(WB + B_XQ);
  u16*   attnb= (u16*)(WB + B_ATTN);
  u16*   qkvb = (u16*)(WB + B_QKV);
  u16*   xb   = (u16*)(WB + B_QKV);
  float* cf   = (float*)(WB + B_QKV);
  float* yt   = (float*)(WB + B_QKV + 33554432LL);
  u16*   vT   = (u16*)(WB + B_VT);
  float* O3   = (float*)(WB + B_O3);
  float* ML3  = (float*)(WB + B_ML3);
  float* ql   = (float*)(WB + B_QL);
  float* kl   = (float*)(WB + B_KL);
  u16*   qlh  = (u16*)(WB + B_QLH);
  u16*   klh  = (u16*)(WB + B_KLH);
  float* a2   = (float*)(WB + B_A2);
  float* a3v  = (float*)(WB + B_A3V);
  float* Z2   = (float*)(WB + B_Z2);
  u16*   Z2T  = (u16*)(WB + B_Z2T);
  float* scal = (float*)(WB + B_SCAL);
  u16*   w1T  = (u16*)(WB + B_W1T);
  u16*   wqT  = (u16*)(WB + B_WQT);
  u16*   woT  = (u16*)(WB + B_WOT);

  u16* a2h  = (u16*)(WB + B_XQ + 0 * MB1);
  u16* a2l  = (u16*)(WB + B_XQ + 1 * MB1);
  u16* z0h  = (u16*)(WB + B_XQ + 2 * MB1);
  u16* z0l  = (u16*)(WB + B_XQ + 3 * MB1);
  u16* z0Th = (u16*)(WB + B_XQ + 4 * MB1);
  u16* z0Tl = (u16*)(WB + B_XQ + 5 * MB1);
  u16* z1h  = (u16*)(WB + B_XQ + 6 * MB1);
  u16* z1l  = (u16*)(WB + B_XQ + 7 * MB1);
  u16* z1Th = (u16*)(WB + B_XQ + 8 * MB1);
  u16* z1Tl = (u16*)(WB + B_XQ + 9 * MB1);
  u16* azh  = (u16*)(WB + B_XQ + 10 * MB1);
  u16* azl  = (u16*)(WB + B_XQ + 11 * MB1);
  u16* azTh = (u16*)(WB + B_XQ + 12 * MB1);
  u16* azTl = (u16*)(WB + B_XQ + 13 * MB1);
  u16* tATh = (u16*)(WB + B_XQ + 14 * MB1);
  u16* tATl = (u16*)(WB + B_XQ + 15 * MB1);
  u16* zah  = (u16*)(WB + B_PV2 + 0 * MB1);
  u16* zal  = (u16*)(WB + B_PV2 + 1 * MB1);
  float* zf = (float*)(WB + B_PV2 + 2 * MB1);

  // ---- fc1 ----
  copy_cls_k<<<1, 256, 0, stream>>>(cls, h);
  cvtbf_k<<<4096, 256, 0, stream>>>(x, xb, 16384LL * 1024);
  tcbf_k<<<dim3(16, 32, 1), 256, 0, stream>>>(fc1_w, w1T, 1024, 512, 512, 1024, 0, 0);
  gemmbf(stream, xb, w1T, h + CDIM, 16384, 512, 1024, 1024, 1024, 512,
         0, 0, 0, 1, fc1_b, nullptr, 0, 1.f, GB_RELU, 1, nullptr, 1);

  for (int L = 0; L < 2; L++){
    ln_pad_k<<<NP, 256, 0, stream>>>(h, l_ng[L], l_nb[L], xq);
    tcbf_k<<<dim3(48, 16, 1), 256, 0, stream>>>(l_qkv[L], wqT, 512, 1536, 1536, 512, 0, 0);
    // qkv: bf16 out, q pre-scaled 0.125, v emitted transposed only (vT)
    gemmbf(stream, xq, wqT, qkvb, NP, 1536, 512, 512, 512, 1536,
           0, 0, 0, 1, nullptr, nullptr, 0, 1.f, GB_STOREBF | GB_QSCALE | GB_SWZ, 1, vT, 1);
    landmark_k<<<LM / 2, 256, 0, stream>>>(qkvb, ql, kl, qlh, klh);
    // a2 = softmax(ql @ kl^T): f32 + hi/lo
    gemm_k<<<dim3(4, 4, 8), 256, 0, stream>>>(ql, kl, a2, LM, LM, DH, DH, DH, LM,
                                              16384, 16384, 65536, 1.f, GF_TRANSB);
    softmax256_k<<<dim3(LM, HEADS), 256, 0, stream>>>(a2, a2h, a2l, scal);
    // pinv init
    pinv_scal_k<<<HEADS, 256, 0, stream>>>(a2, scal);
    z0_k<<<dim3(LM, HEADS), 256, 0, stream>>>(a2, scal, z0h, z0l, z0Th, z0Tl);
    // 6 Newton-Schulz iterations, hi/lo bf16 MFMA, 3 chained GEMMs each
    u16 *zh = z0h, *zl = z0l, *zTh = z0Th, *zTl = z0Tl;
    u16 *nzh = z1h, *nzl = z1l, *nzTh = z1Th, *nzTl = z1Tl;
    dim3 pg(4, 4, HEADS), pg2(4, 4, 2 * HEADS);
    for (int it = 0; it < 6; it++){
      pinvh_k<<<pg, 256, 0, stream>>>(a2h, a2l, zTh, zTl,
                                      azh, azl, azTh, azTl, nullptr,
                                      nullptr, nullptr, 0.f, 1.f, 0.f);
      pinv2_k<<<pg2, 256, 0, stream>>>(azh, azl, azTh, azTl, zh, zl,
                                       tATh, tATl, zah, zal);
      pinvh_k<<<pg, 256, 0, stream>>>(zah, zal, tATh, tATl,
                                      nzh, nzl, nzTh, nzTl,
                                      (it == 5) ? zf : nullptr,
                                      zh, zl, 0.f, -0.25f, 3.25f);
      u16* t;
      t = zh; zh = nzh; nzh = t;   t = zl; zl = nzl; nzl = t;
      t = zTh; zTh = nzTh; nzTh = t; t = zTl; zTl = nzTl; nzTl = t;
    }
    // ---- S3 flash: partials over 13 key chunks, then combine -> a3v ----
    fattn_k<0><<<dim3(4, 13, 8), 256, 0, stream>>>(
        qlh, 64, qkvb + 512, 1536, vT, NP,
        16384, 64, 64LL * NP, 1280,
        nullptr, 0, O3, ML3, 13, 256, 1, nullptr, nullptr);
    comb3_k<<<dim3(64, 8), 256, 0, stream>>>(O3, ML3, a3v);
    // Z2 = pinv(a2) @ a3v (zf f32), then Z2T bf16 per head
    gemm_k<<<dim3(1, 4, 8), 256, 0, stream>>>(zf, a3v, Z2, LM, DH, LM, LM, DH, DH,
                                              65536, 16384, 16384, 1.f, 0);
    tcbf_k<<<dim3(2, 8, 8), 256, 0, stream>>>(Z2, Z2T, 256, 64, 64, 256, 16384, 16384);
    // ---- S1 flash + fused resconv: attn = softmax(q@kl^T)@Z2 + dwconv(v) ----
    fattn_k<1><<<dim3(260, 1, 8), 256, 0, stream>>>(
        qkvb, 1536, klh, 64, Z2T, 256,
        64, 16384, 16384, 256,
        attnb, CDIM, nullptr, nullptr, 1, NP, 0, vT, l_rw[L]);
    // h += attn[-NT:] @ out_w + out_b
    tcbf_k<<<dim3(16, 16, 1), 256, 0, stream>>>(l_ow[L], woT, 512, 512, 512, 512, 0, 0);
    gemmbf(stream, attnb + (long long)PAD * CDIM, woT, h, NT, CDIM, CDIM,
           CDIM, CDIM, CDIM, 0, 0, 0, 1, l_ob[L], nullptr, 0, 1.f, GB_ACCUM, 1, nullptr, 1);

    if (L == 0){
      transpose_k<<<dim3(16, 512), 256, 0, stream>>>(h + CDIM, cf, 16384, CDIM);
      ppeg_k<<<dim3(8, 512), 256, 0, stream>>>(cf, yt, w7, b7, w5, b5, w3, b3);
      transpose_k<<<dim3(512, 16), 256, 0, stream>>>(yt, h + CDIM, CDIM, 16384);
    }
  }

  final_k<<<1, 256, 0, stream>>>(h, norm_g, norm_b, fc2_w, fc2_b, out);
}

// Round 8
// 1240.050 us; speedup vs baseline: 1.0392x; 1.0392x over previous
//
#include <hip/hip_runtime.h>

// ---------------------------------------------------------------------------
// TransMIL forward. Round 16: revert the resconv-into-fattn fusion (both
// variants lost: LDS-conflict then VGPR-pressure/occupancy). Restore lean
// round-5 fattn + separate resconv(vT). Keep qkv dead-v-store skip.
// B=1, N=16384, IN=1024, C=512, heads=8, dh=64, NT=16385, NP=16640,
// landmarks M=256, l=65, pinv iters=6 (hi/lo bf16 MFMA), res conv k=33.
// ---------------------------------------------------------------------------

#define NT 16385
#define NP 16640
#define PAD 255
#define CDIM 512
#define HEADS 8
#define DH 64
#define LM 256
#define LSEG 65

typedef unsigned short u16;
typedef unsigned int u32;
typedef __attribute__((ext_vector_type(8))) short bf16x8;
typedef __attribute__((ext_vector_type(4))) float f32x4;

__device__ __forceinline__ u16 f2b(float f){
  u32 u = __float_as_uint(f);
  u32 r = (u + 0x7FFFu + ((u >> 16) & 1u)) >> 16;
  return (u16)r;
}
__device__ __forceinline__ float b2f(u16 h){ return __uint_as_float(((u32)h) << 16); }

// async global->LDS, 16 B per lane; lds dest = wave-uniform base + lane*16
__device__ __forceinline__ void gload16(const u16* g, u16* l){
  __builtin_amdgcn_global_load_lds(
      (const __attribute__((address_space(1))) u32*)g,
      (__attribute__((address_space(3))) u32*)l, 16, 0, 0);
}

// bijective XCD swizzle (m204): orig dispatch id -> contiguous-per-XCD work id
__device__ __forceinline__ int xcd_swz(int orig, int nwg){
  int qn = nwg >> 3, rn = nwg & 7;
  int xcd = orig & 7, sid = orig >> 3;
  return (xcd < rn ? xcd * (qn + 1) : rn * (qn + 1) + (xcd - rn) * qn) + sid;
}

// ---------------- reductions ----------------
__device__ __forceinline__ float wredSum(float v){
#pragma unroll
  for (int o = 32; o > 0; o >>= 1) v += __shfl_xor(v, o, 64);
  return v;
}
__device__ __forceinline__ float wredMax(float v){
#pragma unroll
  for (int o = 32; o > 0; o >>= 1) v = fmaxf(v, __shfl_xor(v, o, 64));
  return v;
}
__device__ __forceinline__ float bredSum(float v, float* sm){
  v = wredSum(v);
  int w = threadIdx.x >> 6, l = threadIdx.x & 63;
  __syncthreads();
  if (l == 0) sm[w] = v;
  __syncthreads();
  return sm[0] + sm[1] + sm[2] + sm[3];
}
__device__ __forceinline__ float bredMax(float v, float* sm){
  v = wredMax(v);
  int w = threadIdx.x >> 6, l = threadIdx.x & 63;
  __syncthreads();
  if (l == 0) sm[w] = v;
  __syncthreads();
  return fmaxf(fmaxf(sm[0], sm[1]), fmaxf(sm[2], sm[3]));
}

// ---------------- utility ----------------
__global__ __launch_bounds__(256) void copy_cls_k(const float* __restrict__ cls,
                                                  float* __restrict__ h){
  h[threadIdx.x] = cls[threadIdx.x];
  h[threadIdx.x + 256] = cls[threadIdx.x + 256];
}
__global__ __launch_bounds__(256) void cvtbf_k(const float* __restrict__ in,
                                               u16* __restrict__ out, long long n){
  long long i = ((long long)blockIdx.x * 256 + threadIdx.x) * 4;
  long long stride = (long long)gridDim.x * 256 * 4;
  for (; i < n; i += stride){
    float4 v = *(const float4*)(in + i);
    out[i]     = f2b(v.x);
    out[i + 1] = f2b(v.y);
    out[i + 2] = f2b(v.z);
    out[i + 3] = f2b(v.w);
  }
}
// f32 [R][ldin] -> bf16 transposed [C][ldout]
__global__ __launch_bounds__(256) void tcbf_k(const float* __restrict__ in,
    u16* __restrict__ out, int R, int C, int ldin, int ldout,
    long long sIn, long long sOut){
  __shared__ float t[32][33];
  in += (long long)blockIdx.z * sIn; out += (long long)blockIdx.z * sOut;
  int c0 = blockIdx.x * 32, r0 = blockIdx.y * 32;
  int x = threadIdx.x & 31, y = threadIdx.x >> 5;
  for (int yy = y; yy < 32; yy += 8){
    int r = r0 + yy, c = c0 + x;
    if (r < R && c < C) t[yy][x] = in[(long long)r * ldin + c];
  }
  __syncthreads();
  for (int yy = y; yy < 32; yy += 8){
    int c = c0 + yy, r = r0 + x;
    if (c < C && r < R) out[(long long)c * ldout + r] = f2b(t[x][yy]);
  }
}

// ---------------- bf16 MFMA GEMM (m97-style): C = alpha*A@B^T (+bias)(/rowdiv)
#define GB_STOREBF 1
#define GB_RELU    2
#define GB_ACCUM   4
#define GB_ATOMIC  8
#define GB_QSCALE  16   /* multiply cols < 512 by 0.125 (q pre-scale, exact) */
#define GB_SWZ     32   /* XCD-aware block swizzle */

template<int DBUF>
__global__ __launch_bounds__(256) void gemmbf_k(
    const u16* __restrict__ A, const u16* __restrict__ B, void* __restrict__ Cv,
    int M, int N, int K, int lda, int ldb, int ldc,
    long long sA, long long sB, long long sC,
    const float* __restrict__ bias, const float* __restrict__ rowdiv, int sRow,
    float alpha, int flags, int ksplit, u16* __restrict__ vt)
{
  __shared__ __align__(16) u16 sh[DBUF ? 32768 : 16384];   // 64 / 32 KB
  int zb = blockIdx.z / ksplit;
  int ks = blockIdx.z - zb * ksplit;
  A += (long long)zb * sA; B += (long long)zb * sB;
  float* Cf = (float*)Cv + (long long)zb * sC;
  u16*   Ch = (u16*)Cv + (long long)zb * sC;
  int klen = K / ksplit;
  int kbeg = ks * klen, kend = kbeg + klen;
  int tid = threadIdx.x;
  int w = tid >> 6, l = tid & 63;
  int row0, col0;
  if (flags & GB_SWZ){
    int gx = gridDim.x;
    int swz = xcd_swz(blockIdx.y * gx + blockIdx.x, gx * gridDim.y);
    row0 = (swz / gx) * 128; col0 = (swz % gx) * 128;
  } else {
    row0 = blockIdx.y * 128; col0 = blockIdx.x * 128;
  }
  int r8 = l >> 3;
  int csrc = ((l & 7) ^ r8) * 8;
  f32x4 acc[2][8];
#pragma unroll
  for (int i = 0; i < 2; i++)
#pragma unroll
    for (int j = 0; j < 8; j++) acc[i][j] = (f32x4){0.f, 0.f, 0.f, 0.f};

  int mrow = l & 15, q8 = l >> 4;

  auto STAGE = [&](int buf, int k0){
    u16* Asb = sh + buf * 16384;
    u16* Bsb = Asb + 8192;
#pragma unroll
    for (int c = 0; c < 4; c++){
      int r = w * 32 + c * 8;
      int gm = row0 + r + r8; if (gm >= M) gm = M - 1;
      gload16(A + (long long)gm * lda + k0 + csrc, &Asb[r * 64]);
      int gn = col0 + r + r8; if (gn >= N) gn = N - 1;
      gload16(B + (long long)gn * ldb + k0 + csrc, &Bsb[r * 64]);
    }
  };
  auto COMPUTE = [&](int buf){
    const u16* Asb = sh + buf * 16384;
    const u16* Bsb = Asb + 8192;
#pragma unroll
    for (int ks2 = 0; ks2 < 2; ks2++){
      int kc = ks2 * 4 + q8;
      bf16x8 af[2], bfr[8];
#pragma unroll
      for (int i = 0; i < 2; i++){
        int r = w * 32 + i * 16 + mrow;
        af[i] = *(const bf16x8*)&Asb[r * 64 + ((kc ^ (r & 7)) * 8)];
      }
#pragma unroll
      for (int j = 0; j < 8; j++){
        int r = j * 16 + mrow;
        bfr[j] = *(const bf16x8*)&Bsb[r * 64 + ((kc ^ (r & 7)) * 8)];
      }
#pragma unroll
      for (int i = 0; i < 2; i++)
#pragma unroll
        for (int j = 0; j < 8; j++)
          acc[i][j] = __builtin_amdgcn_mfma_f32_16x16x32_bf16(af[i], bfr[j], acc[i][j], 0, 0, 0);
    }
  };

  if constexpr (DBUF){
    STAGE(0, kbeg);
    __syncthreads();
    int cur = 0;
    for (int k0 = kbeg; k0 < kend; k0 += 64){
      if (k0 + 64 < kend) STAGE(cur ^ 1, k0 + 64);
      COMPUTE(cur);
      __syncthreads();
      cur ^= 1;
    }
  } else {
    for (int k0 = kbeg; k0 < kend; k0 += 64){
      STAGE(0, k0);
      __syncthreads();
      COMPUTE(0);
      __syncthreads();
    }
  }

  if (flags & GB_STOREBF){
    // v column-blocks (col0>=1024 with vt) are only consumed via vT -> skip
    // the row-major store entirely for them (block-uniform branch).
    if (!(vt && col0 >= 1024)){
#pragma unroll
      for (int p = 0; p < 2; p++){
        __syncthreads();
#pragma unroll
        for (int i = 0; i < 2; i++)
#pragma unroll
          for (int r = 0; r < 4; r++){
            int lrow = w * 32 + i * 16 + q8 * 4 + r;
            int gm = row0 + lrow;
            float rd = rowdiv ? rowdiv[(long long)zb * sRow + gm] : 1.f;
#pragma unroll
            for (int jj = 0; jj < 4; jj++){
              int j = p * 4 + jj;
              int gn = col0 + j * 16 + mrow;
              float v = alpha * acc[i][j][r];
              if ((flags & GB_QSCALE) && gn < 512) v *= 0.125f;
              if (rowdiv) v /= rd;
              if (bias) v += bias[gn];
              if (flags & GB_RELU) v = fmaxf(v, 0.f);
              sh[lrow * 72 + (j * 16 + mrow - p * 64)] = f2b(v);
            }
          }
        __syncthreads();
#pragma unroll
        for (int it = 0; it < 4; it++){
          int cidx = tid + it * 256;
          int rr = cidx >> 3, c8 = (cidx & 7) * 8;
          int gm = row0 + rr;
          if (gm < M)
            *(uint4*)(Ch + (long long)gm * ldc + col0 + p * 64 + c8) =
                *(const uint4*)&sh[rr * 72 + c8];
        }
      }
    }
    // fused vT output for v column-blocks: vT[(gn-1024)][gm], ld NP
    if (vt && col0 >= 1024){
      int gc0 = col0 - 1024;
#pragma unroll
      for (int p = 0; p < 2; p++){
        __syncthreads();
#pragma unroll
        for (int i = 0; i < 2; i++)
#pragma unroll
          for (int r = 0; r < 4; r++){
            int lrow = w * 32 + i * 16 + q8 * 4 + r;
#pragma unroll
            for (int jj = 0; jj < 4; jj++){
              int j = p * 4 + jj;
              int lcol = j * 16 + mrow - p * 64;
              sh[lcol * 136 + lrow] = f2b(alpha * acc[i][j][r]);
            }
          }
        __syncthreads();
#pragma unroll
        for (int it = 0; it < 4; it++){
          int cidx = tid + it * 256;
          int cc = cidx >> 4, rc = (cidx & 15) * 8;
          *(uint4*)(vt + (long long)(gc0 + p * 64 + cc) * NP + row0 + rc) =
              *(const uint4*)&sh[cc * 136 + rc];
        }
      }
    }
    return;
  }

  if constexpr (DBUF){
    if (!(flags & GB_ATOMIC)){
      float* shf = (float*)sh;
#pragma unroll
      for (int p = 0; p < 2; p++){
        __syncthreads();
#pragma unroll
        for (int i = 0; i < 2; i++)
#pragma unroll
          for (int r = 0; r < 4; r++){
            int lrow = w * 32 + i * 16 + q8 * 4 + r;
            int gm = row0 + lrow;
            int gmc = (gm < M) ? gm : M - 1;
            float rd = rowdiv ? rowdiv[(long long)zb * sRow + gmc] : 1.f;
#pragma unroll
            for (int jj = 0; jj < 4; jj++){
              int j = p * 4 + jj;
              int gn = col0 + j * 16 + mrow;
              float v = alpha * acc[i][j][r];
              if ((flags & GB_QSCALE) && gn < 512) v *= 0.125f;
              if (rowdiv) v /= rd;
              if (bias) v += bias[gn];
              if (flags & GB_RELU) v = fmaxf(v, 0.f);
              shf[lrow * 68 + (j * 16 + mrow - p * 64)] = v;
            }
          }
        __syncthreads();
#pragma unroll
        for (int it = 0; it < 8; it++){
          int cidx = tid + it * 256;
          int rr = cidx >> 4, c4 = (cidx & 15) * 4;
          int gm = row0 + rr;
          if (gm >= M) continue;
          int gn = col0 + p * 64 + c4;
          if (gn + 3 < N){
            float4* dst = (float4*)(Cf + (long long)gm * ldc + gn);
            float4 vv = *(const float4*)&shf[rr * 68 + c4];
            if (flags & GB_ACCUM){
              float4 o = *dst;
              vv.x += o.x; vv.y += o.y; vv.z += o.z; vv.w += o.w;
            }
            *dst = vv;
          } else {
            for (int e = 0; e < 4; e++){
              if (gn + e >= N) break;
              float v = shf[rr * 68 + c4 + e];
              if (flags & GB_ACCUM) Cf[(long long)gm * ldc + gn + e] += v;
              else Cf[(long long)gm * ldc + gn + e] = v;
            }
          }
        }
      }
      return;
    }
  }

#pragma unroll
  for (int i = 0; i < 2; i++){
#pragma unroll
    for (int r = 0; r < 4; r++){
      int gm = row0 + w * 32 + i * 16 + q8 * 4 + r;
      if (gm >= M) continue;
      float rd = rowdiv ? rowdiv[(long long)zb * sRow + gm] : 1.f;
#pragma unroll
      for (int j = 0; j < 8; j++){
        int gn = col0 + j * 16 + mrow;
        if (gn >= N) continue;
        float v = alpha * acc[i][j][r];
        if ((flags & GB_QSCALE) && gn < 512) v *= 0.125f;
        if (rowdiv) v /= rd;
        if (bias) v += bias[gn];
        if (flags & GB_RELU) v = fmaxf(v, 0.f);
        long long ci = (long long)gm * ldc + gn;
        if (flags & GB_ATOMIC) atomicAdd(&Cf[ci], v);
        else if (flags & GB_ACCUM) Cf[ci] += v;
        else Cf[ci] = v;
      }
    }
  }
}

// ---------------- hi/lo bf16 MFMA pinv stage (64x64 tiles, K-dbuf) ---------
__device__ __forceinline__ void pinv_core(
    u16* lds, int cb, int rb, int head,
    const u16* __restrict__ Ah, const u16* __restrict__ Al,
    const u16* __restrict__ BTh, const u16* __restrict__ BTl,
    u16* __restrict__ Chh, u16* __restrict__ Cll,
    u16* __restrict__ CTh, u16* __restrict__ CTl,
    float* __restrict__ Cf,
    const u16* __restrict__ Avh, const u16* __restrict__ Avl,
    float dterm, float sterm, float eterm)
{
  long long off = (long long)head << 16;
  int tid = threadIdx.x, w = tid >> 6, l = tid & 63;
  int row0 = rb * 64, col0 = cb * 64;
  int r8 = l >> 3;
  int csrc = ((l & 7) ^ r8) * 8;
  int mrow = l & 15, q8 = l >> 4;
  f32x4 acc[4];
#pragma unroll
  for (int j = 0; j < 4; j++) acc[j] = (f32x4){0.f, 0.f, 0.f, 0.f};

  auto STAGE = [&](int buf, int k0){
    u16* Ash = lds + buf * 16384;
    u16* Asl = Ash + 4096;
    u16* Bsh = Ash + 8192;
    u16* Bsl = Ash + 12288;
#pragma unroll
    for (int c = 0; c < 2; c++){
      int r = w * 16 + c * 8;
      long long ga = off + (long long)(row0 + r + r8) * 256 + k0 + csrc;
      gload16(Ah + ga, &Ash[r * 64]);
      gload16(Al + ga, &Asl[r * 64]);
      long long gb = off + (long long)(col0 + r + r8) * 256 + k0 + csrc;
      gload16(BTh + gb, &Bsh[r * 64]);
      gload16(BTl + gb, &Bsl[r * 64]);
    }
  };
  auto COMPUTE = [&](int buf){
    const u16* Ash = lds + buf * 16384;
    const u16* Asl = Ash + 4096;
    const u16* Bsh = Ash + 8192;
    const u16* Bsl = Ash + 12288;
#pragma unroll
    for (int ks2 = 0; ks2 < 2; ks2++){
      int kc = ks2 * 4 + q8;
      bf16x8 ah, al, bh[4], bl[4];
      {
        int r = w * 16 + mrow;
        int idx = r * 64 + ((kc ^ (r & 7)) * 8);
        ah = *(const bf16x8*)&Ash[idx];
        al = *(const bf16x8*)&Asl[idx];
      }
#pragma unroll
      for (int j = 0; j < 4; j++){
        int r = j * 16 + mrow;
        int idx = r * 64 + ((kc ^ (r & 7)) * 8);
        bh[j] = *(const bf16x8*)&Bsh[idx];
        bl[j] = *(const bf16x8*)&Bsl[idx];
      }
#pragma unroll
      for (int j = 0; j < 4; j++){
        acc[j] = __builtin_amdgcn_mfma_f32_16x16x32_bf16(ah, bh[j], acc[j], 0, 0, 0);
        acc[j] = __builtin_amdgcn_mfma_f32_16x16x32_bf16(ah, bl[j], acc[j], 0, 0, 0);
        acc[j] = __builtin_amdgcn_mfma_f32_16x16x32_bf16(al, bh[j], acc[j], 0, 0, 0);
      }
    }
  };

  STAGE(0, 0);
  __syncthreads();
  int cur = 0;
  for (int k0 = 0; k0 < 256; k0 += 64){
    if (k0 + 64 < 256) STAGE(cur ^ 1, k0 + 64);
    COMPUTE(cur);
    __syncthreads();
    cur ^= 1;
  }

#pragma unroll
  for (int r = 0; r < 4; r++){
    int gm = row0 + w * 16 + q8 * 4 + r;
#pragma unroll
    for (int j = 0; j < 4; j++){
      int gn = col0 + j * 16 + mrow;
      float v = sterm * acc[j][r];
      if (Avh){
        long long ai = off + (long long)gm * 256 + gn;
        v += eterm * (b2f(Avh[ai]) + b2f(Avl[ai]));
      }
      if (gm == gn) v += dterm;
      acc[j][r] = v;
      long long ci = off + (long long)gm * 256 + gn;
      if (Cf) Cf[ci] = v;
      if (Chh){
        u16 hi = f2b(v);
        Chh[ci] = hi;
        Cll[ci] = f2b(v - b2f(hi));
      }
    }
  }
  if (CTh){
#pragma unroll
    for (int pass = 0; pass < 2; pass++){
      __syncthreads();
#pragma unroll
      for (int r = 0; r < 4; r++){
        int lm = w * 16 + q8 * 4 + r;
#pragma unroll
        for (int j = 0; j < 4; j++){
          int ln = j * 16 + mrow;
          float v = acc[j][r];
          u16 hi = f2b(v);
          lds[ln * 72 + lm] = (pass == 0) ? hi : f2b(v - b2f(hi));
        }
      }
      __syncthreads();
      u16* dst = (pass == 0) ? CTh : CTl;
#pragma unroll
      for (int it = 0; it < 2; it++){
        int cidx = tid + it * 256;
        int rr = cidx >> 3;
        int cc = (cidx & 7) * 8;
        *(uint4*)(dst + off + (long long)(col0 + rr) * 256 + row0 + cc) =
            *(const uint4*)&lds[rr * 72 + cc];
      }
    }
  }
}

__global__ __launch_bounds__(256) void pinvh_k(
    const u16* __restrict__ Ah, const u16* __restrict__ Al,
    const u16* __restrict__ BTh, const u16* __restrict__ BTl,
    u16* __restrict__ Chh, u16* __restrict__ Cll,
    u16* __restrict__ CTh, u16* __restrict__ CTl,
    float* __restrict__ Cf,
    const u16* __restrict__ Avh, const u16* __restrict__ Avl,
    float dterm, float sterm, float eterm)
{
  __shared__ __align__(16) u16 lds[32768];   // 64 KB (2 x 32 KB buffers)
  pinv_core(lds, blockIdx.x, blockIdx.y, blockIdx.z,
            Ah, Al, BTh, BTl, Chh, Cll, CTh, CTl, Cf, Avh, Avl,
            dterm, sterm, eterm);
}
__global__ __launch_bounds__(256) void pinv2_k(
    const u16* __restrict__ azh, const u16* __restrict__ azl,
    const u16* __restrict__ azTh, const u16* __restrict__ azTl,
    const u16* __restrict__ zh, const u16* __restrict__ zl,
    u16* __restrict__ tATh, u16* __restrict__ tATl,
    u16* __restrict__ zah, u16* __restrict__ zal)
{
  __shared__ __align__(16) u16 lds[32768];
  int head = blockIdx.z & 7;
  if (blockIdx.z < 8)
    pinv_core(lds, blockIdx.x, blockIdx.y, head, azh, azl, azTh, azTl,
              nullptr, nullptr, tATh, tATl, nullptr, azh, azl, 15.f, 1.f, -7.f);
  else
    pinv_core(lds, blockIdx.x, blockIdx.y, head, zh, zl, azTh, azTl,
              zah, zal, nullptr, nullptr, nullptr, nullptr, nullptr, 0.f, 1.f, 0.f);
}

// ---------------- f32 GEMM (small: a2, Z2) ----------------
#define GF_TRANSB 1
__global__ __launch_bounds__(256) void gemm_k(
    const float* __restrict__ A, const float* __restrict__ B, float* __restrict__ C,
    int M, int N, int K, int lda, int ldb, int ldc,
    long long sA, long long sB, long long sC, float alpha, int flags)
{
  __shared__ __align__(16) float As[16][68];
  __shared__ __align__(16) float Bs[16][68];
  int zb = blockIdx.z;
  A += (long long)zb * sA; B += (long long)zb * sB; C += (long long)zb * sC;
  int tid = threadIdx.x;
  int tx = tid & 15, ty = tid >> 4;
  int row0 = blockIdx.y * 64, col0 = blockIdx.x * 64;
  float acc[4][4] = {};
  for (int k0 = 0; k0 < K; k0 += 16){
#pragma unroll
    for (int i = 0; i < 4; i++){
      int idx = tid + i * 256;
      int mm = idx >> 4, kk = idx & 15;
      int gm = row0 + mm;
      As[kk][mm] = (gm < M) ? A[(long long)gm * lda + (k0 + kk)] : 0.f;
    }
    if (!(flags & GF_TRANSB)){
#pragma unroll
      for (int i = 0; i < 4; i++){
        int idx = tid + i * 256;
        int kk = idx >> 6, nn = idx & 63;
        int gn = col0 + nn;
        Bs[kk][nn] = (gn < N) ? B[(long long)(k0 + kk) * ldb + gn] : 0.f;
      }
    } else {
#pragma unroll
      for (int i = 0; i < 4; i++){
        int idx = tid + i * 256;
        int nn = idx >> 4, kk = idx & 15;
        int gn = col0 + nn;
        Bs[kk][nn] = (gn < N) ? B[(long long)gn * ldb + (k0 + kk)] : 0.f;
      }
    }
    __syncthreads();
#pragma unroll
    for (int kk = 0; kk < 16; kk++){
      float4 av = *(const float4*)&As[kk][ty * 4];
      float4 bv = *(const float4*)&Bs[kk][tx * 4];
      float a[4] = {av.x, av.y, av.z, av.w};
      float b[4] = {bv.x, bv.y, bv.z, bv.w};
#pragma unroll
      for (int i = 0; i < 4; i++)
#pragma unroll
        for (int j = 0; j < 4; j++)
          acc[i][j] = fmaf(a[i], b[j], acc[i][j]);
    }
    __syncthreads();
  }
#pragma unroll
  for (int i = 0; i < 4; i++){
    int gm = row0 + ty * 4 + i;
    if (gm >= M) continue;
#pragma unroll
    for (int j = 0; j < 4; j++){
      int gn = col0 + tx * 4 + j;
      if (gn >= N) continue;
      C[(long long)gm * ldc + gn] = alpha * acc[i][j];
    }
  }
}

// ---------------- fused flash attention (lean round-5 body) ----------------
__global__ __launch_bounds__(256) void fattn_k(
    const u16* __restrict__ Qp, int ldq,
    const u16* __restrict__ Kp, int ldk,
    const u16* __restrict__ Vp, int ldv,
    long long sQh, long long sKh, long long sVh,
    int keysPerChunk,
    u16* __restrict__ outB, int ldo,
    float* __restrict__ O3, float* __restrict__ ML3, int nchunks, int qrows,
    int mode)
{
  __shared__ u16 Qs[64][72];
  __shared__ u16 Ks[128][72];
  __shared__ u16 Vs[64][136];
  __shared__ u16 Ps[4][16][136];
  int tid = threadIdx.x;
  int w = tid >> 6, l = tid & 63;
  int mrow = l & 15, q8 = l >> 4;
  int gx = gridDim.x, gy = gridDim.y;
  int swz = xcd_swz((blockIdx.z * gy + blockIdx.y) * gx + blockIdx.x,
                    gx * gy * gridDim.z);
  int qt = swz % gx, t2 = swz / gx;
  int ch = t2 % gy, h = t2 / gy;
  const u16* Q = Qp + (long long)h * sQh;
  const u16* K = Kp + (long long)h * sKh;
  const u16* V = Vp + (long long)h * sVh;
  int q0 = qt * 64;
  for (int i = tid; i < 512; i += 256){
    int r = i >> 3, c = (i & 7) * 8;
    *(uint4*)&Qs[r][c] = *(const uint4*)(Q + (long long)(q0 + r) * ldq + c);
  }
  float m_st[4], l_st[4];
  f32x4 acc_o[4];
#pragma unroll
  for (int r = 0; r < 4; r++){
    m_st[r] = -3.0e38f; l_st[r] = 0.f;
    acc_o[r] = (f32x4){0.f, 0.f, 0.f, 0.f};
  }
  int kbase = ch * keysPerChunk;
  for (int kt = 0; kt < keysPerChunk; kt += 128){
    for (int i = tid; i < 1024; i += 256){
      int r = i >> 3, c = (i & 7) * 8;
      *(uint4*)&Ks[r][c] = *(const uint4*)(K + (long long)(kbase + kt + r) * ldk + c);
    }
    for (int i = tid; i < 1024; i += 256){
      int r = i >> 4, c = (i & 15) * 8;
      *(uint4*)&Vs[r][c] = *(const uint4*)(V + (long long)r * ldv + kbase + kt + c);
    }
    __syncthreads();
    f32x4 accs[8];
#pragma unroll
    for (int j = 0; j < 8; j++) accs[j] = (f32x4){0.f, 0.f, 0.f, 0.f};
#pragma unroll
    for (int ks2 = 0; ks2 < 2; ks2++){
      bf16x8 af = *(const bf16x8*)&Qs[w * 16 + mrow][ks2 * 32 + q8 * 8];
#pragma unroll
      for (int j = 0; j < 8; j++){
        bf16x8 bfv = *(const bf16x8*)&Ks[j * 16 + mrow][ks2 * 32 + q8 * 8];
        accs[j] = __builtin_amdgcn_mfma_f32_16x16x32_bf16(af, bfv, accs[j], 0, 0, 0);
      }
    }
#pragma unroll
    for (int r = 0; r < 4; r++){
      float tm = -3.0e38f;
#pragma unroll
      for (int j = 0; j < 8; j++) tm = fmaxf(tm, accs[j][r]);
      tm = fmaxf(tm, __shfl_xor(tm, 1, 64));
      tm = fmaxf(tm, __shfl_xor(tm, 2, 64));
      tm = fmaxf(tm, __shfl_xor(tm, 4, 64));
      tm = fmaxf(tm, __shfl_xor(tm, 8, 64));
      float mn = fmaxf(m_st[r], tm);
      float al = __expf(m_st[r] - mn);
      m_st[r] = mn;
      float rs = 0.f;
#pragma unroll
      for (int j = 0; j < 8; j++){
        float e = __expf(accs[j][r] - mn);
        accs[j][r] = e;
        rs += e;
      }
      rs += __shfl_xor(rs, 1, 64);
      rs += __shfl_xor(rs, 2, 64);
      rs += __shfl_xor(rs, 4, 64);
      rs += __shfl_xor(rs, 8, 64);
      l_st[r] = al * l_st[r] + rs;
#pragma unroll
      for (int j = 0; j < 4; j++) acc_o[j][r] *= al;
    }
#pragma unroll
    for (int j = 0; j < 8; j++)
#pragma unroll
      for (int r = 0; r < 4; r++)
        Ps[w][q8 * 4 + r][j * 16 + mrow] = f2b(accs[j][r]);
    __syncthreads();
#pragma unroll
    for (int kc = 0; kc < 4; kc++){
      bf16x8 af = *(const bf16x8*)&Ps[w][mrow][kc * 32 + q8 * 8];
#pragma unroll
      for (int j = 0; j < 4; j++){
        bf16x8 bfv = *(const bf16x8*)&Vs[j * 16 + mrow][kc * 32 + q8 * 8];
        acc_o[j] = __builtin_amdgcn_mfma_f32_16x16x32_bf16(af, bfv, acc_o[j], 0, 0, 0);
      }
    }
    __syncthreads();
  }
  if (mode == 0){
#pragma unroll
    for (int r = 0; r < 4; r++){
      int grow = q0 + w * 16 + q8 * 4 + r;
      float inv = 1.f / l_st[r];
#pragma unroll
      for (int j = 0; j < 4; j++)
        outB[(long long)grow * ldo + h * 64 + j * 16 + mrow] = f2b(acc_o[j][r] * inv);
    }
  } else {
#pragma unroll
    for (int r = 0; r < 4; r++){
      int row = q0 + w * 16 + q8 * 4 + r;
      long long b = ((long long)h * nchunks + ch) * qrows + row;
#pragma unroll
      for (int j = 0; j < 4; j++)
        O3[b * 64 + j * 16 + mrow] = acc_o[j][r];
      if (mrow == 0){
        ML3[b * 2] = m_st[r];
        ML3[b * 2 + 1] = l_st[r];
      }
    }
  }
}

// combine S3 partials
__global__ __launch_bounds__(256) void comb3_k(
    const float* __restrict__ O3, const float* __restrict__ ML3,
    float* __restrict__ a3v)
{
  int h = blockIdx.y;
  int row = blockIdx.x * 4 + (threadIdx.x >> 6);
  int d = threadIdx.x & 63;
  float m = -3.0e38f;
  for (int c = 0; c < 13; c++)
    m = fmaxf(m, ML3[(((long long)h * 13 + c) * 256 + row) * 2]);
  float l = 0.f, o = 0.f;
  for (int c = 0; c < 13; c++){
    long long b = ((long long)h * 13 + c) * 256 + row;
    float wgt = __expf(ML3[b * 2] - m);
    l += wgt * ML3[b * 2 + 1];
    o += wgt * O3[b * 64 + d];
  }
  a3v[((long long)h * 256 + row) * 64 + d] = o / l;
}

// ---------------- layernorm + front-pad -> bf16 xq (NP x 512) --------------
__global__ __launch_bounds__(256) void ln_pad_k(
    const float* __restrict__ h, const float* __restrict__ g,
    const float* __restrict__ b, u16* __restrict__ out)
{
  __shared__ float sm[4];
  int row = blockIdx.x, tid = threadIdx.x;
  u16* o = out + (long long)row * CDIM;
  if (row < PAD){ o[tid] = 0; o[tid + 256] = 0; return; }
  const float* x = h + (long long)(row - PAD) * CDIM;
  float v0 = x[tid], v1 = x[tid + 256];
  float s = bredSum(v0 + v1, sm);
  float s2 = bredSum(v0 * v0 + v1 * v1, sm);
  float mean = s * (1.f / 512.f);
  float var = s2 * (1.f / 512.f) - mean * mean;
  float rstd = rsqrtf(var + 1e-5f);
  o[tid] = f2b((v0 - mean) * rstd * g[tid] + b[tid]);
  o[tid + 256] = f2b((v1 - mean) * rstd * g[tid + 256] + b[tid + 256]);
}

// ---------------- landmark means (vectorized; q pre-scaled by 0.125) -------
__global__ __launch_bounds__(256) void landmark_k(
    const u16* __restrict__ qkv, float* __restrict__ ql, float* __restrict__ kl,
    u16* __restrict__ qlh, u16* __restrict__ klh)
{
  int m = blockIdx.x * 2 + (threadIdx.x >> 7);
  int c8 = (threadIdx.x & 127) * 8;
  const u16* base = qkv + (long long)(m * LSEG) * 1536 + c8;
  float s[8] = {};
  for (int j = 0; j < LSEG; j++){
    uint4 pk = *(const uint4*)(base + (long long)j * 1536);
    const u16* pv = (const u16*)&pk;
#pragma unroll
    for (int e = 0; e < 8; e++) s[e] += b2f(pv[e]);
  }
#pragma unroll
  for (int e = 0; e < 8; e++){
    int col = c8 + e;
    float v = s[e] * (1.f / 65.f);
    int h = (col & 511) >> 6, d = col & 63;
    int idx = (h * LM + m) * DH + d;
    if (col < 512){ ql[idx] = v; qlh[idx] = f2b(v); }
    else          { kl[idx] = v; klh[idx] = f2b(v); }
  }
}

// ---------------- softmax over rows of 256 (f32 + hi/lo bf16 out) ----------
__global__ __launch_bounds__(256) void softmax256_k(float* __restrict__ S,
    u16* __restrict__ a2h, u16* __restrict__ a2l, float* __restrict__ scal)
{
  __shared__ float sm[4];
  int i = blockIdx.x, h = blockIdx.y, j = threadIdx.x;
  if (i == 0 && h == 0 && j < 2) scal[j] = 0.f;
  long long idx = ((long long)h * LM + i) * 256 + j;
  float v = S[idx];
  float m = bredMax(v, sm);
  float e = __expf(v - m);
  float s = bredSum(e, sm);
  float p = e / s;
  S[idx] = p;
  u16 hi = f2b(p);
  a2h[idx] = hi;
  a2l[idx] = f2b(p - b2f(hi));
}

// ---------------- pinv scale factors ----------------
__global__ __launch_bounds__(256) void pinv_scal_k(
    const float* __restrict__ a2, float* __restrict__ scal)
{
  __shared__ float sm[4];
  int h = blockIdx.x, i = threadIdx.x;
  const float* Ah = a2 + (long long)h * 65536;
  float rs = 0.f, cs = 0.f;
  for (int j = 0; j < 256; j++){
    rs += fabsf(Ah[i * 256 + j]);
    cs += fabsf(Ah[j * 256 + i]);
  }
  float rmax = bredMax(rs, sm);
  __syncthreads();
  float cmax = bredMax(cs, sm);
  if (i == 0){
    atomicMax((int*)&scal[0], __float_as_int(rmax));
    atomicMax((int*)&scal[1], __float_as_int(cmax));
  }
}

// z0 = a2^T * inv (hi/lo + transposed hi/lo)
__global__ __launch_bounds__(256) void z0_k(
    const float* __restrict__ a2, const float* __restrict__ scal,
    u16* __restrict__ zh, u16* __restrict__ zl,
    u16* __restrict__ zTh, u16* __restrict__ zTl)
{
  int ri = blockIdx.x, h = blockIdx.y, j = threadIdx.x;
  float inv = 1.f / (scal[0] * scal[1]);
  long long base = ((long long)h * LM + ri) * 256;
  float v = a2[base + j] * inv;
  u16 hi = f2b(v), lo = f2b(v - b2f(hi));
  zTh[base + j] = hi; zTl[base + j] = lo;
  long long tb = ((long long)h * LM + j) * 256 + ri;
  zh[tb] = hi; zl[tb] = lo;
}

// ---------------- depthwise 33-tap residual conv (reads contiguous vT) -----
__global__ __launch_bounds__(256) void resconv_k(
    const u16* __restrict__ vT, const float* __restrict__ rw,
    u16* __restrict__ attn)
{
  int c = blockIdx.x * 256 + threadIdx.x;
  int s0 = blockIdx.y * 8;
  int h = c >> 6;
  float w[33];
#pragma unroll
  for (int t = 0; t < 33; t++) w[t] = rw[h * 33 + t];
  float vr[40];
  const u16* vrow = vT + (long long)c * NP;
  if (s0 >= 16 && s0 + 24 <= NP){
#pragma unroll
    for (int q = 0; q < 5; q++){
      uint4 pk = *(const uint4*)(vrow + s0 - 16 + q * 8);
      const u16* pv = (const u16*)&pk;
#pragma unroll
      for (int e = 0; e < 8; e++) vr[q * 8 + e] = b2f(pv[e]);
    }
  } else {
#pragma unroll
    for (int j = 0; j < 40; j++){
      int s = s0 - 16 + j;
      vr[j] = (s >= 0 && s < NP) ? b2f(vrow[s]) : 0.f;
    }
  }
#pragma unroll
  for (int i = 0; i < 8; i++){
    float a = 0.f;
#pragma unroll
    for (int t = 0; t < 33; t++) a = fmaf(vr[i + t], w[t], a);
    long long idx = (long long)(s0 + i) * CDIM + c;
    attn[idx] = f2b(b2f(attn[idx]) + a);
  }
}

// ---------------- f32 32x32 transpose ----------------
__global__ __launch_bounds__(256) void transpose_k(
    const float* __restrict__ in, float* __restrict__ out, int R, int Cc)
{
  __shared__ float t[32][33];
  int bx = blockIdx.x * 32, by = blockIdx.y * 32;
  int x = threadIdx.x & 31, y4 = threadIdx.x >> 5;
  for (int yy = y4; yy < 32; yy += 8){
    int r = by + yy, c = bx + x;
    if (r < R && c < Cc) t[yy][x] = in[(long long)r * Cc + c];
  }
  __syncthreads();
  for (int yy = y4; yy < 32; yy += 8){
    int r = bx + yy, c = by + x;
    if (r < Cc && c < R) out[(long long)r * R + c] = t[x][yy];
  }
}

// ---------------- fused PPEG (16x128 strip, register column window) --------
__global__ __launch_bounds__(256) void ppeg_k(
    const float* __restrict__ cf, float* __restrict__ yt,
    const float* __restrict__ w7, const float* __restrict__ b7,
    const float* __restrict__ w5, const float* __restrict__ b5,
    const float* __restrict__ w3, const float* __restrict__ b3)
{
  __shared__ float tile[22][136];   // rows ys-3..ys+18, cols -3..130
  __shared__ float wsh[84];
  int c = blockIdx.y;
  int ys = blockIdx.x * 16;
  int tid = threadIdx.x;
  const float* img = cf + (long long)c * 16384;
  if (tid < 49) wsh[tid] = w7[c * 49 + tid];
  else if (tid >= 64 && tid < 89) wsh[49 + tid - 64] = w5[c * 25 + (tid - 64)];
  else if (tid >= 96 && tid < 105) wsh[74 + tid - 96] = w3[c * 9 + (tid - 96)];
  else if (tid == 128) wsh[83] = b7[c] + b5[c] + b3[c];
  for (int i = tid; i < 22 * 134; i += 256){
    int yy = i / 134, xx = i - yy * 134;
    int gy = ys - 3 + yy, gx = xx - 3;
    tile[yy][xx] = (gy >= 0 && gy < 128 && gx >= 0 && gx < 128) ? img[gy * 128 + gx] : 0.f;
  }
  __syncthreads();
  int x = tid & 127;
  int yo = (tid >> 7) * 8;     // 0 or 8
  float acc[8];
#pragma unroll
  for (int i = 0; i < 8; i++) acc[i] = tile[yo + i + 3][x + 3] + wsh[83];
#pragma unroll
  for (int kx = 0; kx < 7; kx++){
    float col[14];
#pragma unroll
    for (int t = 0; t < 14; t++) col[t] = tile[yo + t][x + kx];
    float wc7[7];
#pragma unroll
    for (int ky = 0; ky < 7; ky++) wc7[ky] = wsh[ky * 7 + kx];
#pragma unroll
    for (int i = 0; i < 8; i++)
#pragma unroll
      for (int ky = 0; ky < 7; ky++)
        acc[i] = fmaf(col[i + ky], wc7[ky], acc[i]);
    if (kx >= 1 && kx <= 5){
      float wc5[5];
#pragma unroll
      for (int ky = 0; ky < 5; ky++) wc5[ky] = wsh[49 + ky * 5 + (kx - 1)];
#pragma unroll
      for (int i = 0; i < 8; i++)
#pragma unroll
        for (int ky = 0; ky < 5; ky++)
          acc[i] = fmaf(col[i + 1 + ky], wc5[ky], acc[i]);
    }
    if (kx >= 2 && kx <= 4){
      float wc3[3];
#pragma unroll
      for (int ky = 0; ky < 3; ky++) wc3[ky] = wsh[74 + ky * 3 + (kx - 2)];
#pragma unroll
      for (int i = 0; i < 8; i++)
#pragma unroll
        for (int ky = 0; ky < 3; ky++)
          acc[i] = fmaf(col[i + 2 + ky], wc3[ky], acc[i]);
    }
  }
  float* dst = yt + (long long)c * 16384 + (ys + yo) * 128 + x;
#pragma unroll
  for (int i = 0; i < 8; i++) dst[i * 128] = acc[i];
}

// ---------------- final: LN(h[0]) @ fc2 + b ----------------
__global__ __launch_bounds__(256) void final_k(
    const float* __restrict__ h, const float* __restrict__ g,
    const float* __restrict__ b, const float* __restrict__ w,
    const float* __restrict__ bias, float* __restrict__ out)
{
  __shared__ float sm[4];
  __shared__ float pj[256][4];
  int tid = threadIdx.x;
  float v0 = h[tid], v1 = h[tid + 256];
  float s = bredSum(v0 + v1, sm);
  float s2 = bredSum(v0 * v0 + v1 * v1, sm);
  float mean = s * (1.f / 512.f);
  float var = s2 * (1.f / 512.f) - mean * mean;
  float rstd = rsqrtf(var + 1e-5f);
  float n0 = (v0 - mean) * rstd * g[tid] + b[tid];
  float n1 = (v1 - mean) * rstd * g[tid + 256] + b[tid + 256];
#pragma unroll
  for (int j = 0; j < 4; j++)
    pj[tid][j] = n0 * w[tid * 4 + j] + n1 * w[(tid + 256) * 4 + j];
  __syncthreads();
  if (tid < 4){
    float acc = 0.f;
    for (int k = 0; k < 256; k++) acc += pj[k][tid];
    out[tid] = acc + bias[tid];
  }
}

// ===========================================================================
// host side
// ===========================================================================
static inline void gemmbf(hipStream_t st, const u16* A, const u16* B, void* C,
                          int M, int N, int K, int lda, int ldb, int ldc,
                          long long sA, long long sB, long long sC, int batch,
                          const float* bias, const float* rowdiv, int sRow,
                          float alpha, int flags, int ksplit, u16* vt, int dbuf)
{
  dim3 grid((N + 127) / 128, (M + 127) / 128, batch * ksplit);
  if (dbuf)
    gemmbf_k<1><<<grid, 256, 0, st>>>(A, B, C, M, N, K, lda, ldb, ldc, sA, sB, sC,
                                      bias, rowdiv, sRow, alpha, flags, ksplit, vt);
  else
    gemmbf_k<0><<<grid, 256, 0, st>>>(A, B, C, M, N, K, lda, ldb, ldc, sA, sB, sC,
                                      bias, rowdiv, sRow, alpha, flags, ksplit, vt);
}

// workspace byte offsets
#define B_H     0LL
#define B_XQ    33556480LL     /* xq; after qkv, hosts pinv hi/lo arrays (16MB) */
#define B_ATTN  50595840LL
#define B_QKV   67635200LL     /* also xb; also cf/yt for PPEG */
#define B_VT    118753280LL
#define B_O3    135792640LL
#define B_ML3   142608384LL
#define B_QL    169871360LL
#define B_KL    170395648LL
#define B_QLH   170919936LL
#define B_KLH   171182080LL
#define B_A2    171444224LL
#define B_PV2   173541376LL    /* zah(1M), zal(1M), zf f32(2M) */
#define B_A3V   184027136LL
#define B_Z2    184551424LL
#define B_Z2T   185075712LL
#define B_SCAL  185604096LL
#define B_W1T   185604352LL
#define B_WQT   186652928LL
#define B_WOT   188225792LL
#define WS_REQ  188750080LL
#define MB1     1048576LL

extern "C" void kernel_launch(void* const* d_in, const int* in_sizes, int n_in,
                              void* d_out, int out_size, void* d_ws, size_t ws_size,
                              hipStream_t stream)
{
  (void)in_sizes; (void)n_in; (void)out_size;
  if (ws_size < (size_t)WS_REQ) return;

  const float* x      = (const float*)d_in[0];
  const float* fc1_w  = (const float*)d_in[1];
  const float* fc1_b  = (const float*)d_in[2];
  const float* cls    = (const float*)d_in[3];
  const float* l_ng[2]  = {(const float*)d_in[4],  (const float*)d_in[10]};
  const float* l_nb[2]  = {(const float*)d_in[5],  (const float*)d_in[11]};
  const float* l_qkv[2] = {(const float*)d_in[6],  (const float*)d_in[12]};
  const float* l_ow[2]  = {(const float*)d_in[7],  (const float*)d_in[13]};
  const float* l_ob[2]  = {(const float*)d_in[8],  (const float*)d_in[14]};
  const float* l_rw[2]  = {(const float*)d_in[9],  (const float*)d_in[15]};
  const float* w7 = (const float*)d_in[16];
  const float* b7 = (const float*)d_in[17];
  const float* w5 = (const float*)d_in[18];
  const float* b5 = (const float*)d_in[19];
  const float* w3 = (const float*)d_in[20];
  const float* b3 = (const float*)d_in[21];
  const float* norm_g = (const float*)d_in[22];
  const float* norm_b = (const float*)d_in[23];
  const float* fc2_w  = (const float*)d_in[24];
  const float* fc2_b  = (const float*)d_in[25];
  float* out = (float*)d_out;

  char* WB = (char*)d_ws;
  float* h    = (float*)(WB + B_H);
  u16*   xq   = (u16*)(WB + B_XQ);
  u16*   attnb= (u16*)(WB + B_ATTN);
  u16*   qkvb = (u16*)(WB + B_QKV);
  u16*   xb   = (u16*)(WB + B_QKV);
  float* cf   = (float*)(WB + B_QKV);
  float* yt   = (float*)(WB + B_QKV + 33554432LL);
  u16*   vT   = (u16*)(WB + B_VT);
  float* O3   = (float*)(WB + B_O3);
  float* ML3  = (float*)(WB + B_ML3);
  float* ql   = (float*)(WB + B_QL);
  float* kl   = (float*)(WB + B_KL);
  u16*   qlh  = (u16*)(WB + B_QLH);
  u16*   klh  = (u16*)(WB + B_KLH);
  float* a2   = (float*)(WB + B_A2);
  float* a3v  = (float*)(WB + B_A3V);
  float* Z2   = (float*)(WB + B_Z2);
  u16*   Z2T  = (u16*)(WB + B_Z2T);
  float* scal = (float*)(WB + B_SCAL);
  u16*   w1T  = (u16*)(WB + B_W1T);
  u16*   wqT  = (u16*)(WB + B_WQT);
  u16*   woT  = (u16*)(WB + B_WOT);

  u16* a2h  = (u16*)(WB + B_XQ + 0 * MB1);
  u16* a2l  = (u16*)(WB + B_XQ + 1 * MB1);
  u16* z0h  = (u16*)(WB + B_XQ + 2 * MB1);
  u16* z0l  = (u16*)(WB + B_XQ + 3 * MB1);
  u16* z0Th = (u16*)(WB + B_XQ + 4 * MB1);
  u16* z0Tl = (u16*)(WB + B_XQ + 5 * MB1);
  u16* z1h  = (u16*)(WB + B_XQ + 6 * MB1);
  u16* z1l  = (u16*)(WB + B_XQ + 7 * MB1);
  u16* z1Th = (u16*)(WB + B_XQ + 8 * MB1);
  u16* z1Tl = (u16*)(WB + B_XQ + 9 * MB1);
  u16* azh  = (u16*)(WB + B_XQ + 10 * MB1);
  u16* azl  = (u16*)(WB + B_XQ + 11 * MB1);
  u16* azTh = (u16*)(WB + B_XQ + 12 * MB1);
  u16* azTl = (u16*)(WB + B_XQ + 13 * MB1);
  u16* tATh = (u16*)(WB + B_XQ + 14 * MB1);
  u16* tATl = (u16*)(WB + B_XQ + 15 * MB1);
  u16* zah  = (u16*)(WB + B_PV2 + 0 * MB1);
  u16* zal  = (u16*)(WB + B_PV2 + 1 * MB1);
  float* zf = (float*)(WB + B_PV2 + 2 * MB1);

  // ---- fc1 ----
  copy_cls_k<<<1, 256, 0, stream>>>(cls, h);
  cvtbf_k<<<4096, 256, 0, stream>>>(x, xb, 16384LL * 1024);
  tcbf_k<<<dim3(16, 32, 1), 256, 0, stream>>>(fc1_w, w1T, 1024, 512, 512, 1024, 0, 0);
  gemmbf(stream, xb, w1T, h + CDIM, 16384, 512, 1024, 1024, 1024, 512,
         0, 0, 0, 1, fc1_b, nullptr, 0, 1.f, GB_RELU, 1, nullptr, 1);

  for (int L = 0; L < 2; L++){
    ln_pad_k<<<NP, 256, 0, stream>>>(h, l_ng[L], l_nb[L], xq);
    tcbf_k<<<dim3(48, 16, 1), 256, 0, stream>>>(l_qkv[L], wqT, 512, 1536, 1536, 512, 0, 0);
    // qkv: bf16 out, q pre-scaled 0.125, v emitted transposed only (vT)
    gemmbf(stream, xq, wqT, qkvb, NP, 1536, 512, 512, 512, 1536,
           0, 0, 0, 1, nullptr, nullptr, 0, 1.f, GB_STOREBF | GB_QSCALE | GB_SWZ, 1, vT, 1);
    landmark_k<<<LM / 2, 256, 0, stream>>>(qkvb, ql, kl, qlh, klh);
    // a2 = softmax(ql @ kl^T): f32 + hi/lo
    gemm_k<<<dim3(4, 4, 8), 256, 0, stream>>>(ql, kl, a2, LM, LM, DH, DH, DH, LM,
                                              16384, 16384, 65536, 1.f, GF_TRANSB);
    softmax256_k<<<dim3(LM, HEADS), 256, 0, stream>>>(a2, a2h, a2l, scal);
    // pinv init
    pinv_scal_k<<<HEADS, 256, 0, stream>>>(a2, scal);
    z0_k<<<dim3(LM, HEADS), 256, 0, stream>>>(a2, scal, z0h, z0l, z0Th, z0Tl);
    // 6 Newton-Schulz iterations, hi/lo bf16 MFMA, 3 chained GEMMs each
    u16 *zh = z0h, *zl = z0l, *zTh = z0Th, *zTl = z0Tl;
    u16 *nzh = z1h, *nzl = z1l, *nzTh = z1Th, *nzTl = z1Tl;
    dim3 pg(4, 4, HEADS), pg2(4, 4, 2 * HEADS);
    for (int it = 0; it < 6; it++){
      pinvh_k<<<pg, 256, 0, stream>>>(a2h, a2l, zTh, zTl,
                                      azh, azl, azTh, azTl, nullptr,
                                      nullptr, nullptr, 0.f, 1.f, 0.f);
      pinv2_k<<<pg2, 256, 0, stream>>>(azh, azl, azTh, azTl, zh, zl,
                                       tATh, tATl, zah, zal);
      pinvh_k<<<pg, 256, 0, stream>>>(zah, zal, tATh, tATl,
                                      nzh, nzl, nzTh, nzTl,
                                      (it == 5) ? zf : nullptr,
                                      zh, zl, 0.f, -0.25f, 3.25f);
      u16* t;
      t = zh; zh = nzh; nzh = t;   t = zl; zl = nzl; nzl = t;
      t = zTh; zTh = nzTh; nzTh = t; t = zTl; zTl = nzTl; nzTl = t;
    }
    // ---- S3 flash: partials over 13 key chunks, then combine -> a3v ----
    fattn_k<<<dim3(4, 13, 8), 256, 0, stream>>>(
        qlh, 64, qkvb + 512, 1536, vT, NP,
        16384, 64, 64LL * NP, 1280,
        nullptr, 0, O3, ML3, 13, 256, 1);
    comb3_k<<<dim3(64, 8), 256, 0, stream>>>(O3, ML3, a3v);
    // Z2 = pinv(a2) @ a3v (zf f32), then Z2T bf16 per head
    gemm_k<<<dim3(1, 4, 8), 256, 0, stream>>>(zf, a3v, Z2, LM, DH, LM, LM, DH, DH,
                                              65536, 16384, 16384, 1.f, 0);
    tcbf_k<<<dim3(2, 8, 8), 256, 0, stream>>>(Z2, Z2T, 256, 64, 64, 256, 16384, 16384);
    // ---- S1 flash: attn = softmax(q @ kl^T) @ Z2, exact (256 keys) ----
    fattn_k<<<dim3(260, 1, 8), 256, 0, stream>>>(
        qkvb, 1536, klh, 64, Z2T, 256,
        64, 16384, 16384, 256,
        attnb, CDIM, nullptr, nullptr, 1, NP, 0);
    // attn += depthwise 33-tap conv of v (reads contiguous vT rows)
    resconv_k<<<dim3(2, NP / 8), 256, 0, stream>>>(vT, l_rw[L], attnb);
    // h += attn[-NT:] @ out_w + out_b
    tcbf_k<<<dim3(16, 16, 1), 256, 0, stream>>>(l_ow[L], woT, 512, 512, 512, 512, 0, 0);
    gemmbf(stream, attnb + (long long)PAD * CDIM, woT, h, NT, CDIM, CDIM,
           CDIM, CDIM, CDIM, 0, 0, 0, 1, l_ob[L], nullptr, 0, 1.f, GB_ACCUM, 1, nullptr, 1);

    if (L == 0){
      transpose_k<<<dim3(16, 512), 256, 0, stream>>>(h + CDIM, cf, 16384, CDIM);
      ppeg_k<<<dim3(8, 512), 256, 0, stream>>>(cf, yt, w7, b7, w5, b5, w3, b3);
      transpose_k<<<dim3(512, 16), 256, 0, stream>>>(yt, h + CDIM, CDIM, 16384);
    }
  }

  final_k<<<1, 256, 0, stream>>>(h, norm_g, norm_b, fc2_w, fc2_b, out);
}

// Round 11
// 1194.908 us; speedup vs baseline: 1.0784x; 1.0378x over previous
//
#include <hip/hip_runtime.h>

// ---------------------------------------------------------------------------
// TransMIL forward. Round 18: round-16 baseline (1240us, known-good) + ONLY
// the pinv head-affinity decode (head = blockid&7 -> one head per XCD L2).
// The round-17 S3 26-chunk split + O3/ML3 relocation is deferred: that kernel
// failed the container twice; this minimal diff disambiguates kernel vs infra.
// B=1, N=16384, IN=1024, C=512, heads=8, dh=64, NT=16385, NP=16640,
// landmarks M=256, l=65, pinv iters=6 (hi/lo bf16 MFMA), res conv k=33.
// ---------------------------------------------------------------------------

#define NT 16385
#define NP 16640
#define PAD 255
#define CDIM 512
#define HEADS 8
#define DH 64
#define LM 256
#define LSEG 65

typedef unsigned short u16;
typedef unsigned int u32;
typedef __attribute__((ext_vector_type(8))) short bf16x8;
typedef __attribute__((ext_vector_type(4))) float f32x4;

__device__ __forceinline__ u16 f2b(float f){
  u32 u = __float_as_uint(f);
  u32 r = (u + 0x7FFFu + ((u >> 16) & 1u)) >> 16;
  return (u16)r;
}
__device__ __forceinline__ float b2f(u16 h){ return __uint_as_float(((u32)h) << 16); }

// async global->LDS, 16 B per lane; lds dest = wave-uniform base + lane*16
__device__ __forceinline__ void gload16(const u16* g, u16* l){
  __builtin_amdgcn_global_load_lds(
      (const __attribute__((address_space(1))) u32*)g,
      (__attribute__((address_space(3))) u32*)l, 16, 0, 0);
}

// bijective XCD swizzle (m204): orig dispatch id -> contiguous-per-XCD work id
__device__ __forceinline__ int xcd_swz(int orig, int nwg){
  int qn = nwg >> 3, rn = nwg & 7;
  int xcd = orig & 7, sid = orig >> 3;
  return (xcd < rn ? xcd * (qn + 1) : rn * (qn + 1) + (xcd - rn) * qn) + sid;
}

// ---------------- reductions ----------------
__device__ __forceinline__ float wredSum(float v){
#pragma unroll
  for (int o = 32; o > 0; o >>= 1) v += __shfl_xor(v, o, 64);
  return v;
}
__device__ __forceinline__ float wredMax(float v){
#pragma unroll
  for (int o = 32; o > 0; o >>= 1) v = fmaxf(v, __shfl_xor(v, o, 64));
  return v;
}
__device__ __forceinline__ float bredSum(float v, float* sm){
  v = wredSum(v);
  int w = threadIdx.x >> 6, l = threadIdx.x & 63;
  __syncthreads();
  if (l == 0) sm[w] = v;
  __syncthreads();
  return sm[0] + sm[1] + sm[2] + sm[3];
}
__device__ __forceinline__ float bredMax(float v, float* sm){
  v = wredMax(v);
  int w = threadIdx.x >> 6, l = threadIdx.x & 63;
  __syncthreads();
  if (l == 0) sm[w] = v;
  __syncthreads();
  return fmaxf(fmaxf(sm[0], sm[1]), fmaxf(sm[2], sm[3]));
}

// ---------------- utility ----------------
__global__ __launch_bounds__(256) void copy_cls_k(const float* __restrict__ cls,
                                                  float* __restrict__ h){
  h[threadIdx.x] = cls[threadIdx.x];
  h[threadIdx.x + 256] = cls[threadIdx.x + 256];
}
__global__ __launch_bounds__(256) void cvtbf_k(const float* __restrict__ in,
                                               u16* __restrict__ out, long long n){
  long long i = ((long long)blockIdx.x * 256 + threadIdx.x) * 4;
  long long stride = (long long)gridDim.x * 256 * 4;
  for (; i < n; i += stride){
    float4 v = *(const float4*)(in + i);
    out[i]     = f2b(v.x);
    out[i + 1] = f2b(v.y);
    out[i + 2] = f2b(v.z);
    out[i + 3] = f2b(v.w);
  }
}
// f32 [R][ldin] -> bf16 transposed [C][ldout]
__global__ __launch_bounds__(256) void tcbf_k(const float* __restrict__ in,
    u16* __restrict__ out, int R, int C, int ldin, int ldout,
    long long sIn, long long sOut){
  __shared__ float t[32][33];
  in += (long long)blockIdx.z * sIn; out += (long long)blockIdx.z * sOut;
  int c0 = blockIdx.x * 32, r0 = blockIdx.y * 32;
  int x = threadIdx.x & 31, y = threadIdx.x >> 5;
  for (int yy = y; yy < 32; yy += 8){
    int r = r0 + yy, c = c0 + x;
    if (r < R && c < C) t[yy][x] = in[(long long)r * ldin + c];
  }
  __syncthreads();
  for (int yy = y; yy < 32; yy += 8){
    int c = c0 + yy, r = r0 + x;
    if (c < C && r < R) out[(long long)c * ldout + r] = f2b(t[x][yy]);
  }
}

// ---------------- bf16 MFMA GEMM (m97-style): C = alpha*A@B^T (+bias)(/rowdiv)
#define GB_STOREBF 1
#define GB_RELU    2
#define GB_ACCUM   4
#define GB_ATOMIC  8
#define GB_QSCALE  16   /* multiply cols < 512 by 0.125 (q pre-scale, exact) */
#define GB_SWZ     32   /* XCD-aware block swizzle */

template<int DBUF>
__global__ __launch_bounds__(256) void gemmbf_k(
    const u16* __restrict__ A, const u16* __restrict__ B, void* __restrict__ Cv,
    int M, int N, int K, int lda, int ldb, int ldc,
    long long sA, long long sB, long long sC,
    const float* __restrict__ bias, const float* __restrict__ rowdiv, int sRow,
    float alpha, int flags, int ksplit, u16* __restrict__ vt)
{
  __shared__ __align__(16) u16 sh[DBUF ? 32768 : 16384];   // 64 / 32 KB
  int zb = blockIdx.z / ksplit;
  int ks = blockIdx.z - zb * ksplit;
  A += (long long)zb * sA; B += (long long)zb * sB;
  float* Cf = (float*)Cv + (long long)zb * sC;
  u16*   Ch = (u16*)Cv + (long long)zb * sC;
  int klen = K / ksplit;
  int kbeg = ks * klen, kend = kbeg + klen;
  int tid = threadIdx.x;
  int w = tid >> 6, l = tid & 63;
  int row0, col0;
  if (flags & GB_SWZ){
    int gx = gridDim.x;
    int swz = xcd_swz(blockIdx.y * gx + blockIdx.x, gx * gridDim.y);
    row0 = (swz / gx) * 128; col0 = (swz % gx) * 128;
  } else {
    row0 = blockIdx.y * 128; col0 = blockIdx.x * 128;
  }
  int r8 = l >> 3;
  int csrc = ((l & 7) ^ r8) * 8;
  f32x4 acc[2][8];
#pragma unroll
  for (int i = 0; i < 2; i++)
#pragma unroll
    for (int j = 0; j < 8; j++) acc[i][j] = (f32x4){0.f, 0.f, 0.f, 0.f};

  int mrow = l & 15, q8 = l >> 4;

  auto STAGE = [&](int buf, int k0){
    u16* Asb = sh + buf * 16384;
    u16* Bsb = Asb + 8192;
#pragma unroll
    for (int c = 0; c < 4; c++){
      int r = w * 32 + c * 8;
      int gm = row0 + r + r8; if (gm >= M) gm = M - 1;
      gload16(A + (long long)gm * lda + k0 + csrc, &Asb[r * 64]);
      int gn = col0 + r + r8; if (gn >= N) gn = N - 1;
      gload16(B + (long long)gn * ldb + k0 + csrc, &Bsb[r * 64]);
    }
  };
  auto COMPUTE = [&](int buf){
    const u16* Asb = sh + buf * 16384;
    const u16* Bsb = Asb + 8192;
#pragma unroll
    for (int ks2 = 0; ks2 < 2; ks2++){
      int kc = ks2 * 4 + q8;
      bf16x8 af[2], bfr[8];
#pragma unroll
      for (int i = 0; i < 2; i++){
        int r = w * 32 + i * 16 + mrow;
        af[i] = *(const bf16x8*)&Asb[r * 64 + ((kc ^ (r & 7)) * 8)];
      }
#pragma unroll
      for (int j = 0; j < 8; j++){
        int r = j * 16 + mrow;
        bfr[j] = *(const bf16x8*)&Bsb[r * 64 + ((kc ^ (r & 7)) * 8)];
      }
#pragma unroll
      for (int i = 0; i < 2; i++)
#pragma unroll
        for (int j = 0; j < 8; j++)
          acc[i][j] = __builtin_amdgcn_mfma_f32_16x16x32_bf16(af[i], bfr[j], acc[i][j], 0, 0, 0);
    }
  };

  if constexpr (DBUF){
    STAGE(0, kbeg);
    __syncthreads();
    int cur = 0;
    for (int k0 = kbeg; k0 < kend; k0 += 64){
      if (k0 + 64 < kend) STAGE(cur ^ 1, k0 + 64);
      COMPUTE(cur);
      __syncthreads();
      cur ^= 1;
    }
  } else {
    for (int k0 = kbeg; k0 < kend; k0 += 64){
      STAGE(0, k0);
      __syncthreads();
      COMPUTE(0);
      __syncthreads();
    }
  }

  if (flags & GB_STOREBF){
    // v column-blocks (col0>=1024 with vt) are only consumed via vT -> skip
    // the row-major store entirely for them (block-uniform branch).
    if (!(vt && col0 >= 1024)){
#pragma unroll
      for (int p = 0; p < 2; p++){
        __syncthreads();
#pragma unroll
        for (int i = 0; i < 2; i++)
#pragma unroll
          for (int r = 0; r < 4; r++){
            int lrow = w * 32 + i * 16 + q8 * 4 + r;
            int gm = row0 + lrow;
            float rd = rowdiv ? rowdiv[(long long)zb * sRow + gm] : 1.f;
#pragma unroll
            for (int jj = 0; jj < 4; jj++){
              int j = p * 4 + jj;
              int gn = col0 + j * 16 + mrow;
              float v = alpha * acc[i][j][r];
              if ((flags & GB_QSCALE) && gn < 512) v *= 0.125f;
              if (rowdiv) v /= rd;
              if (bias) v += bias[gn];
              if (flags & GB_RELU) v = fmaxf(v, 0.f);
              sh[lrow * 72 + (j * 16 + mrow - p * 64)] = f2b(v);
            }
          }
        __syncthreads();
#pragma unroll
        for (int it = 0; it < 4; it++){
          int cidx = tid + it * 256;
          int rr = cidx >> 3, c8 = (cidx & 7) * 8;
          int gm = row0 + rr;
          if (gm < M)
            *(uint4*)(Ch + (long long)gm * ldc + col0 + p * 64 + c8) =
                *(const uint4*)&sh[rr * 72 + c8];
        }
      }
    }
    // fused vT output for v column-blocks: vT[(gn-1024)][gm], ld NP
    if (vt && col0 >= 1024){
      int gc0 = col0 - 1024;
#pragma unroll
      for (int p = 0; p < 2; p++){
        __syncthreads();
#pragma unroll
        for (int i = 0; i < 2; i++)
#pragma unroll
          for (int r = 0; r < 4; r++){
            int lrow = w * 32 + i * 16 + q8 * 4 + r;
#pragma unroll
            for (int jj = 0; jj < 4; jj++){
              int j = p * 4 + jj;
              int lcol = j * 16 + mrow - p * 64;
              sh[lcol * 136 + lrow] = f2b(alpha * acc[i][j][r]);
            }
          }
        __syncthreads();
#pragma unroll
        for (int it = 0; it < 4; it++){
          int cidx = tid + it * 256;
          int cc = cidx >> 4, rc = (cidx & 15) * 8;
          *(uint4*)(vt + (long long)(gc0 + p * 64 + cc) * NP + row0 + rc) =
              *(const uint4*)&sh[cc * 136 + rc];
        }
      }
    }
    return;
  }

  if constexpr (DBUF){
    if (!(flags & GB_ATOMIC)){
      float* shf = (float*)sh;
#pragma unroll
      for (int p = 0; p < 2; p++){
        __syncthreads();
#pragma unroll
        for (int i = 0; i < 2; i++)
#pragma unroll
          for (int r = 0; r < 4; r++){
            int lrow = w * 32 + i * 16 + q8 * 4 + r;
            int gm = row0 + lrow;
            int gmc = (gm < M) ? gm : M - 1;
            float rd = rowdiv ? rowdiv[(long long)zb * sRow + gmc] : 1.f;
#pragma unroll
            for (int jj = 0; jj < 4; jj++){
              int j = p * 4 + jj;
              int gn = col0 + j * 16 + mrow;
              float v = alpha * acc[i][j][r];
              if ((flags & GB_QSCALE) && gn < 512) v *= 0.125f;
              if (rowdiv) v /= rd;
              if (bias) v += bias[gn];
              if (flags & GB_RELU) v = fmaxf(v, 0.f);
              shf[lrow * 68 + (j * 16 + mrow - p * 64)] = v;
            }
          }
        __syncthreads();
#pragma unroll
        for (int it = 0; it < 8; it++){
          int cidx = tid + it * 256;
          int rr = cidx >> 4, c4 = (cidx & 15) * 4;
          int gm = row0 + rr;
          if (gm >= M) continue;
          int gn = col0 + p * 64 + c4;
          if (gn + 3 < N){
            float4* dst = (float4*)(Cf + (long long)gm * ldc + gn);
            float4 vv = *(const float4*)&shf[rr * 68 + c4];
            if (flags & GB_ACCUM){
              float4 o = *dst;
              vv.x += o.x; vv.y += o.y; vv.z += o.z; vv.w += o.w;
            }
            *dst = vv;
          } else {
            for (int e = 0; e < 4; e++){
              if (gn + e >= N) break;
              float v = shf[rr * 68 + c4 + e];
              if (flags & GB_ACCUM) Cf[(long long)gm * ldc + gn + e] += v;
              else Cf[(long long)gm * ldc + gn + e] = v;
            }
          }
        }
      }
      return;
    }
  }

#pragma unroll
  for (int i = 0; i < 2; i++){
#pragma unroll
    for (int r = 0; r < 4; r++){
      int gm = row0 + w * 32 + i * 16 + q8 * 4 + r;
      if (gm >= M) continue;
      float rd = rowdiv ? rowdiv[(long long)zb * sRow + gm] : 1.f;
#pragma unroll
      for (int j = 0; j < 8; j++){
        int gn = col0 + j * 16 + mrow;
        if (gn >= N) continue;
        float v = alpha * acc[i][j][r];
        if ((flags & GB_QSCALE) && gn < 512) v *= 0.125f;
        if (rowdiv) v /= rd;
        if (bias) v += bias[gn];
        if (flags & GB_RELU) v = fmaxf(v, 0.f);
        long long ci = (long long)gm * ldc + gn;
        if (flags & GB_ATOMIC) atomicAdd(&Cf[ci], v);
        else if (flags & GB_ACCUM) Cf[ci] += v;
        else Cf[ci] = v;
      }
    }
  }
}

// ---------------- hi/lo bf16 MFMA pinv stage (64x64 tiles, K-dbuf) ---------
__device__ __forceinline__ void pinv_core(
    u16* lds, int cb, int rb, int head,
    const u16* __restrict__ Ah, const u16* __restrict__ Al,
    const u16* __restrict__ BTh, const u16* __restrict__ BTl,
    u16* __restrict__ Chh, u16* __restrict__ Cll,
    u16* __restrict__ CTh, u16* __restrict__ CTl,
    float* __restrict__ Cf,
    const u16* __restrict__ Avh, const u16* __restrict__ Avl,
    float dterm, float sterm, float eterm)
{
  long long off = (long long)head << 16;
  int tid = threadIdx.x, w = tid >> 6, l = tid & 63;
  int row0 = rb * 64, col0 = cb * 64;
  int r8 = l >> 3;
  int csrc = ((l & 7) ^ r8) * 8;
  int mrow = l & 15, q8 = l >> 4;
  f32x4 acc[4];
#pragma unroll
  for (int j = 0; j < 4; j++) acc[j] = (f32x4){0.f, 0.f, 0.f, 0.f};

  auto STAGE = [&](int buf, int k0){
    u16* Ash = lds + buf * 16384;
    u16* Asl = Ash + 4096;
    u16* Bsh = Ash + 8192;
    u16* Bsl = Ash + 12288;
#pragma unroll
    for (int c = 0; c < 2; c++){
      int r = w * 16 + c * 8;
      long long ga = off + (long long)(row0 + r + r8) * 256 + k0 + csrc;
      gload16(Ah + ga, &Ash[r * 64]);
      gload16(Al + ga, &Asl[r * 64]);
      long long gb = off + (long long)(col0 + r + r8) * 256 + k0 + csrc;
      gload16(BTh + gb, &Bsh[r * 64]);
      gload16(BTl + gb, &Bsl[r * 64]);
    }
  };
  auto COMPUTE = [&](int buf){
    const u16* Ash = lds + buf * 16384;
    const u16* Asl = Ash + 4096;
    const u16* Bsh = Ash + 8192;
    const u16* Bsl = Ash + 12288;
#pragma unroll
    for (int ks2 = 0; ks2 < 2; ks2++){
      int kc = ks2 * 4 + q8;
      bf16x8 ah, al, bh[4], bl[4];
      {
        int r = w * 16 + mrow;
        int idx = r * 64 + ((kc ^ (r & 7)) * 8);
        ah = *(const bf16x8*)&Ash[idx];
        al = *(const bf16x8*)&Asl[idx];
      }
#pragma unroll
      for (int j = 0; j < 4; j++){
        int r = j * 16 + mrow;
        int idx = r * 64 + ((kc ^ (r & 7)) * 8);
        bh[j] = *(const bf16x8*)&Bsh[idx];
        bl[j] = *(const bf16x8*)&Bsl[idx];
      }
#pragma unroll
      for (int j = 0; j < 4; j++){
        acc[j] = __builtin_amdgcn_mfma_f32_16x16x32_bf16(ah, bh[j], acc[j], 0, 0, 0);
        acc[j] = __builtin_amdgcn_mfma_f32_16x16x32_bf16(ah, bl[j], acc[j], 0, 0, 0);
        acc[j] = __builtin_amdgcn_mfma_f32_16x16x32_bf16(al, bh[j], acc[j], 0, 0, 0);
      }
    }
  };

  STAGE(0, 0);
  __syncthreads();
  int cur = 0;
  for (int k0 = 0; k0 < 256; k0 += 64){
    if (k0 + 64 < 256) STAGE(cur ^ 1, k0 + 64);
    COMPUTE(cur);
    __syncthreads();
    cur ^= 1;
  }

#pragma unroll
  for (int r = 0; r < 4; r++){
    int gm = row0 + w * 16 + q8 * 4 + r;
#pragma unroll
    for (int j = 0; j < 4; j++){
      int gn = col0 + j * 16 + mrow;
      float v = sterm * acc[j][r];
      if (Avh){
        long long ai = off + (long long)gm * 256 + gn;
        v += eterm * (b2f(Avh[ai]) + b2f(Avl[ai]));
      }
      if (gm == gn) v += dterm;
      acc[j][r] = v;
      long long ci = off + (long long)gm * 256 + gn;
      if (Cf) Cf[ci] = v;
      if (Chh){
        u16 hi = f2b(v);
        Chh[ci] = hi;
        Cll[ci] = f2b(v - b2f(hi));
      }
    }
  }
  if (CTh){
#pragma unroll
    for (int pass = 0; pass < 2; pass++){
      __syncthreads();
#pragma unroll
      for (int r = 0; r < 4; r++){
        int lm = w * 16 + q8 * 4 + r;
#pragma unroll
        for (int j = 0; j < 4; j++){
          int ln = j * 16 + mrow;
          float v = acc[j][r];
          u16 hi = f2b(v);
          lds[ln * 72 + lm] = (pass == 0) ? hi : f2b(v - b2f(hi));
        }
      }
      __syncthreads();
      u16* dst = (pass == 0) ? CTh : CTl;
#pragma unroll
      for (int it = 0; it < 2; it++){
        int cidx = tid + it * 256;
        int rr = cidx >> 3;
        int cc = (cidx & 7) * 8;
        *(uint4*)(dst + off + (long long)(col0 + rr) * 256 + row0 + cc) =
            *(const uint4*)&lds[rr * 72 + cc];
      }
    }
  }
}

// head-affinity decode: head = d&7 (= XCD under round-robin dispatch) so each
// XCD keeps one head's panels resident in its L2. Bijective over the grid.
__global__ __launch_bounds__(256) void pinvh_k(
    const u16* __restrict__ Ah, const u16* __restrict__ Al,
    const u16* __restrict__ BTh, const u16* __restrict__ BTl,
    u16* __restrict__ Chh, u16* __restrict__ Cll,
    u16* __restrict__ CTh, u16* __restrict__ CTl,
    float* __restrict__ Cf,
    const u16* __restrict__ Avh, const u16* __restrict__ Avl,
    float dterm, float sterm, float eterm)
{
  __shared__ __align__(16) u16 lds[32768];   // 64 KB (2 x 32 KB buffers)
  int d = (blockIdx.z * gridDim.y + blockIdx.y) * gridDim.x + blockIdx.x;
  int head = d & 7, tile = d >> 3;           // grid 128 blocks: tile 0..15
  pinv_core(lds, tile & 3, tile >> 2, head,
            Ah, Al, BTh, BTl, Chh, Cll, CTh, CTl, Cf, Avh, Avl,
            dterm, sterm, eterm);
}
__global__ __launch_bounds__(256) void pinv2_k(
    const u16* __restrict__ azh, const u16* __restrict__ azl,
    const u16* __restrict__ azTh, const u16* __restrict__ azTl,
    const u16* __restrict__ zh, const u16* __restrict__ zl,
    u16* __restrict__ tATh, u16* __restrict__ tATl,
    u16* __restrict__ zah, u16* __restrict__ zal)
{
  __shared__ __align__(16) u16 lds[32768];
  int d = (blockIdx.z * gridDim.y + blockIdx.y) * gridDim.x + blockIdx.x;
  int slice = d & 15, tile = d >> 4;         // grid 256 blocks: tile 0..15
  int head = slice & 7;
  if (slice < 8)
    pinv_core(lds, tile & 3, tile >> 2, head, azh, azl, azTh, azTl,
              nullptr, nullptr, tATh, tATl, nullptr, azh, azl, 15.f, 1.f, -7.f);
  else
    pinv_core(lds, tile & 3, tile >> 2, head, zh, zl, azTh, azTl,
              zah, zal, nullptr, nullptr, nullptr, nullptr, nullptr, 0.f, 1.f, 0.f);
}

// ---------------- f32 GEMM (small: a2, Z2) ----------------
#define GF_TRANSB 1
__global__ __launch_bounds__(256) void gemm_k(
    const float* __restrict__ A, const float* __restrict__ B, float* __restrict__ C,
    int M, int N, int K, int lda, int ldb, int ldc,
    long long sA, long long sB, long long sC, float alpha, int flags)
{
  __shared__ __align__(16) float As[16][68];
  __shared__ __align__(16) float Bs[16][68];
  int zb = blockIdx.z;
  A += (long long)zb * sA; B += (long long)zb * sB; C += (long long)zb * sC;
  int tid = threadIdx.x;
  int tx = tid & 15, ty = tid >> 4;
  int row0 = blockIdx.y * 64, col0 = blockIdx.x * 64;
  float acc[4][4] = {};
  for (int k0 = 0; k0 < K; k0 += 16){
#pragma unroll
    for (int i = 0; i < 4; i++){
      int idx = tid + i * 256;
      int mm = idx >> 4, kk = idx & 15;
      int gm = row0 + mm;
      As[kk][mm] = (gm < M) ? A[(long long)gm * lda + (k0 + kk)] : 0.f;
    }
    if (!(flags & GF_TRANSB)){
#pragma unroll
      for (int i = 0; i < 4; i++){
        int idx = tid + i * 256;
        int kk = idx >> 6, nn = idx & 63;
        int gn = col0 + nn;
        Bs[kk][nn] = (gn < N) ? B[(long long)(k0 + kk) * ldb + gn] : 0.f;
      }
    } else {
#pragma unroll
      for (int i = 0; i < 4; i++){
        int idx = tid + i * 256;
        int nn = idx >> 4, kk = idx & 15;
        int gn = col0 + nn;
        Bs[kk][nn] = (gn < N) ? B[(long long)gn * ldb + (k0 + kk)] : 0.f;
      }
    }
    __syncthreads();
#pragma unroll
    for (int kk = 0; kk < 16; kk++){
      float4 av = *(const float4*)&As[kk][ty * 4];
      float4 bv = *(const float4*)&Bs[kk][tx * 4];
      float a[4] = {av.x, av.y, av.z, av.w};
      float b[4] = {bv.x, bv.y, bv.z, bv.w};
#pragma unroll
      for (int i = 0; i < 4; i++)
#pragma unroll
        for (int j = 0; j < 4; j++)
          acc[i][j] = fmaf(a[i], b[j], acc[i][j]);
    }
    __syncthreads();
  }
#pragma unroll
  for (int i = 0; i < 4; i++){
    int gm = row0 + ty * 4 + i;
    if (gm >= M) continue;
#pragma unroll
    for (int j = 0; j < 4; j++){
      int gn = col0 + tx * 4 + j;
      if (gn >= N) continue;
      C[(long long)gm * ldc + gn] = alpha * acc[i][j];
    }
  }
}

// ---------------- fused flash attention (lean round-5 body) ----------------
__global__ __launch_bounds__(256) void fattn_k(
    const u16* __restrict__ Qp, int ldq,
    const u16* __restrict__ Kp, int ldk,
    const u16* __restrict__ Vp, int ldv,
    long long sQh, long long sKh, long long sVh,
    int keysPerChunk,
    u16* __restrict__ outB, int ldo,
    float* __restrict__ O3, float* __restrict__ ML3, int nchunks, int qrows,
    int mode)
{
  __shared__ u16 Qs[64][72];
  __shared__ u16 Ks[128][72];
  __shared__ u16 Vs[64][136];
  __shared__ u16 Ps[4][16][136];
  int tid = threadIdx.x;
  int w = tid >> 6, l = tid & 63;
  int mrow = l & 15, q8 = l >> 4;
  int gx = gridDim.x, gy = gridDim.y;
  int swz = xcd_swz((blockIdx.z * gy + blockIdx.y) * gx + blockIdx.x,
                    gx * gy * gridDim.z);
  int qt = swz % gx, t2 = swz / gx;
  int ch = t2 % gy, h = t2 / gy;
  const u16* Q = Qp + (long long)h * sQh;
  const u16* K = Kp + (long long)h * sKh;
  const u16* V = Vp + (long long)h * sVh;
  int q0 = qt * 64;
  for (int i = tid; i < 512; i += 256){
    int r = i >> 3, c = (i & 7) * 8;
    *(uint4*)&Qs[r][c] = *(const uint4*)(Q + (long long)(q0 + r) * ldq + c);
  }
  float m_st[4], l_st[4];
  f32x4 acc_o[4];
#pragma unroll
  for (int r = 0; r < 4; r++){
    m_st[r] = -3.0e38f; l_st[r] = 0.f;
    acc_o[r] = (f32x4){0.f, 0.f, 0.f, 0.f};
  }
  int kbase = ch * keysPerChunk;
  for (int kt = 0; kt < keysPerChunk; kt += 128){
    for (int i = tid; i < 1024; i += 256){
      int r = i >> 3, c = (i & 7) * 8;
      *(uint4*)&Ks[r][c] = *(const uint4*)(K + (long long)(kbase + kt + r) * ldk + c);
    }
    for (int i = tid; i < 1024; i += 256){
      int r = i >> 4, c = (i & 15) * 8;
      *(uint4*)&Vs[r][c] = *(const uint4*)(V + (long long)r * ldv + kbase + kt + c);
    }
    __syncthreads();
    f32x4 accs[8];
#pragma unroll
    for (int j = 0; j < 8; j++) accs[j] = (f32x4){0.f, 0.f, 0.f, 0.f};
#pragma unroll
    for (int ks2 = 0; ks2 < 2; ks2++){
      bf16x8 af = *(const bf16x8*)&Qs[w * 16 + mrow][ks2 * 32 + q8 * 8];
#pragma unroll
      for (int j = 0; j < 8; j++){
        bf16x8 bfv = *(const bf16x8*)&Ks[j * 16 + mrow][ks2 * 32 + q8 * 8];
        accs[j] = __builtin_amdgcn_mfma_f32_16x16x32_bf16(af, bfv, accs[j], 0, 0, 0);
      }
    }
#pragma unroll
    for (int r = 0; r < 4; r++){
      float tm = -3.0e38f;
#pragma unroll
      for (int j = 0; j < 8; j++) tm = fmaxf(tm, accs[j][r]);
      tm = fmaxf(tm, __shfl_xor(tm, 1, 64));
      tm = fmaxf(tm, __shfl_xor(tm, 2, 64));
      tm = fmaxf(tm, __shfl_xor(tm, 4, 64));
      tm = fmaxf(tm, __shfl_xor(tm, 8, 64));
      float mn = fmaxf(m_st[r], tm);
      float al = __expf(m_st[r] - mn);
      m_st[r] = mn;
      float rs = 0.f;
#pragma unroll
      for (int j = 0; j < 8; j++){
        float e = __expf(accs[j][r] - mn);
        accs[j][r] = e;
        rs += e;
      }
      rs += __shfl_xor(rs, 1, 64);
      rs += __shfl_xor(rs, 2, 64);
      rs += __shfl_xor(rs, 4, 64);
      rs += __shfl_xor(rs, 8, 64);
      l_st[r] = al * l_st[r] + rs;
#pragma unroll
      for (int j = 0; j < 4; j++) acc_o[j][r] *= al;
    }
#pragma unroll
    for (int j = 0; j < 8; j++)
#pragma unroll
      for (int r = 0; r < 4; r++)
        Ps[w][q8 * 4 + r][j * 16 + mrow] = f2b(accs[j][r]);
    __syncthreads();
#pragma unroll
    for (int kc = 0; kc < 4; kc++){
      bf16x8 af = *(const bf16x8*)&Ps[w][mrow][kc * 32 + q8 * 8];
#pragma unroll
      for (int j = 0; j < 4; j++){
        bf16x8 bfv = *(const bf16x8*)&Vs[j * 16 + mrow][kc * 32 + q8 * 8];
        acc_o[j] = __builtin_amdgcn_mfma_f32_16x16x32_bf16(af, bfv, acc_o[j], 0, 0, 0);
      }
    }
    __syncthreads();
  }
  if (mode == 0){
#pragma unroll
    for (int r = 0; r < 4; r++){
      int grow = q0 + w * 16 + q8 * 4 + r;
      float inv = 1.f / l_st[r];
#pragma unroll
      for (int j = 0; j < 4; j++)
        outB[(long long)grow * ldo + h * 64 + j * 16 + mrow] = f2b(acc_o[j][r] * inv);
    }
  } else {
#pragma unroll
    for (int r = 0; r < 4; r++){
      int row = q0 + w * 16 + q8 * 4 + r;
      long long b = ((long long)h * nchunks + ch) * qrows + row;
#pragma unroll
      for (int j = 0; j < 4; j++)
        O3[b * 64 + j * 16 + mrow] = acc_o[j][r];
      if (mrow == 0){
        ML3[b * 2] = m_st[r];
        ML3[b * 2 + 1] = l_st[r];
      }
    }
  }
}

// combine S3 partials
__global__ __launch_bounds__(256) void comb3_k(
    const float* __restrict__ O3, const float* __restrict__ ML3,
    float* __restrict__ a3v)
{
  int h = blockIdx.y;
  int row = blockIdx.x * 4 + (threadIdx.x >> 6);
  int d = threadIdx.x & 63;
  float m = -3.0e38f;
  for (int c = 0; c < 13; c++)
    m = fmaxf(m, ML3[(((long long)h * 13 + c) * 256 + row) * 2]);
  float l = 0.f, o = 0.f;
  for (int c = 0; c < 13; c++){
    long long b = ((long long)h * 13 + c) * 256 + row;
    float wgt = __expf(ML3[b * 2] - m);
    l += wgt * ML3[b * 2 + 1];
    o += wgt * O3[b * 64 + d];
  }
  a3v[((long long)h * 256 + row) * 64 + d] = o / l;
}

// ---------------- layernorm + front-pad -> bf16 xq (NP x 512) --------------
__global__ __launch_bounds__(256) void ln_pad_k(
    const float* __restrict__ h, const float* __restrict__ g,
    const float* __restrict__ b, u16* __restrict__ out)
{
  __shared__ float sm[4];
  int row = blockIdx.x, tid = threadIdx.x;
  u16* o = out + (long long)row * CDIM;
  if (row < PAD){ o[tid] = 0; o[tid + 256] = 0; return; }
  const float* x = h + (long long)(row - PAD) * CDIM;
  float v0 = x[tid], v1 = x[tid + 256];
  float s = bredSum(v0 + v1, sm);
  float s2 = bredSum(v0 * v0 + v1 * v1, sm);
  float mean = s * (1.f / 512.f);
  float var = s2 * (1.f / 512.f) - mean * mean;
  float rstd = rsqrtf(var + 1e-5f);
  o[tid] = f2b((v0 - mean) * rstd * g[tid] + b[tid]);
  o[tid + 256] = f2b((v1 - mean) * rstd * g[tid + 256] + b[tid + 256]);
}

// ---------------- landmark means (vectorized; q pre-scaled by 0.125) -------
__global__ __launch_bounds__(256) void landmark_k(
    const u16* __restrict__ qkv, float* __restrict__ ql, float* __restrict__ kl,
    u16* __restrict__ qlh, u16* __restrict__ klh)
{
  int m = blockIdx.x * 2 + (threadIdx.x >> 7);
  int c8 = (threadIdx.x & 127) * 8;
  const u16* base = qkv + (long long)(m * LSEG) * 1536 + c8;
  float s[8] = {};
  for (int j = 0; j < LSEG; j++){
    uint4 pk = *(const uint4*)(base + (long long)j * 1536);
    const u16* pv = (const u16*)&pk;
#pragma unroll
    for (int e = 0; e < 8; e++) s[e] += b2f(pv[e]);
  }
#pragma unroll
  for (int e = 0; e < 8; e++){
    int col = c8 + e;
    float v = s[e] * (1.f / 65.f);
    int h = (col & 511) >> 6, d = col & 63;
    int idx = (h * LM + m) * DH + d;
    if (col < 512){ ql[idx] = v; qlh[idx] = f2b(v); }
    else          { kl[idx] = v; klh[idx] = f2b(v); }
  }
}

// ---------------- softmax over rows of 256 (f32 + hi/lo bf16 out) ----------
__global__ __launch_bounds__(256) void softmax256_k(float* __restrict__ S,
    u16* __restrict__ a2h, u16* __restrict__ a2l, float* __restrict__ scal)
{
  __shared__ float sm[4];
  int i = blockIdx.x, h = blockIdx.y, j = threadIdx.x;
  if (i == 0 && h == 0 && j < 2) scal[j] = 0.f;
  long long idx = ((long long)h * LM + i) * 256 + j;
  float v = S[idx];
  float m = bredMax(v, sm);
  float e = __expf(v - m);
  float s = bredSum(e, sm);
  float p = e / s;
  S[idx] = p;
  u16 hi = f2b(p);
  a2h[idx] = hi;
  a2l[idx] = f2b(p - b2f(hi));
}

// ---------------- pinv scale factors ----------------
__global__ __launch_bounds__(256) void pinv_scal_k(
    const float* __restrict__ a2, float* __restrict__ scal)
{
  __shared__ float sm[4];
  int h = blockIdx.x, i = threadIdx.x;
  const float* Ah = a2 + (long long)h * 65536;
  float rs = 0.f, cs = 0.f;
  for (int j = 0; j < 256; j++){
    rs += fabsf(Ah[i * 256 + j]);
    cs += fabsf(Ah[j * 256 + i]);
  }
  float rmax = bredMax(rs, sm);
  __syncthreads();
  float cmax = bredMax(cs, sm);
  if (i == 0){
    atomicMax((int*)&scal[0], __float_as_int(rmax));
    atomicMax((int*)&scal[1], __float_as_int(cmax));
  }
}

// z0 = a2^T * inv (hi/lo + transposed hi/lo)
__global__ __launch_bounds__(256) void z0_k(
    const float* __restrict__ a2, const float* __restrict__ scal,
    u16* __restrict__ zh, u16* __restrict__ zl,
    u16* __restrict__ zTh, u16* __restrict__ zTl)
{
  int ri = blockIdx.x, h = blockIdx.y, j = threadIdx.x;
  float inv = 1.f / (scal[0] * scal[1]);
  long long base = ((long long)h * LM + ri) * 256;
  float v = a2[base + j] * inv;
  u16 hi = f2b(v), lo = f2b(v - b2f(hi));
  zTh[base + j] = hi; zTl[base + j] = lo;
  long long tb = ((long long)h * LM + j) * 256 + ri;
  zh[tb] = hi; zl[tb] = lo;
}

// ---------------- depthwise 33-tap residual conv (reads contiguous vT) -----
__global__ __launch_bounds__(256) void resconv_k(
    const u16* __restrict__ vT, const float* __restrict__ rw,
    u16* __restrict__ attn)
{
  int c = blockIdx.x * 256 + threadIdx.x;
  int s0 = blockIdx.y * 8;
  int h = c >> 6;
  float w[33];
#pragma unroll
  for (int t = 0; t < 33; t++) w[t] = rw[h * 33 + t];
  float vr[40];
  const u16* vrow = vT + (long long)c * NP;
  if (s0 >= 16 && s0 + 24 <= NP){
#pragma unroll
    for (int q = 0; q < 5; q++){
      uint4 pk = *(const uint4*)(vrow + s0 - 16 + q * 8);
      const u16* pv = (const u16*)&pk;
#pragma unroll
      for (int e = 0; e < 8; e++) vr[q * 8 + e] = b2f(pv[e]);
    }
  } else {
#pragma unroll
    for (int j = 0; j < 40; j++){
      int s = s0 - 16 + j;
      vr[j] = (s >= 0 && s < NP) ? b2f(vrow[s]) : 0.f;
    }
  }
#pragma unroll
  for (int i = 0; i < 8; i++){
    float a = 0.f;
#pragma unroll
    for (int t = 0; t < 33; t++) a = fmaf(vr[i + t], w[t], a);
    long long idx = (long long)(s0 + i) * CDIM + c;
    attn[idx] = f2b(b2f(attn[idx]) + a);
  }
}

// ---------------- f32 32x32 transpose ----------------
__global__ __launch_bounds__(256) void transpose_k(
    const float* __restrict__ in, float* __restrict__ out, int R, int Cc)
{
  __shared__ float t[32][33];
  int bx = blockIdx.x * 32, by = blockIdx.y * 32;
  int x = threadIdx.x & 31, y4 = threadIdx.x >> 5;
  for (int yy = y4; yy < 32; yy += 8){
    int r = by + yy, c = bx + x;
    if (r < R && c < Cc) t[yy][x] = in[(long long)r * Cc + c];
  }
  __syncthreads();
  for (int yy = y4; yy < 32; yy += 8){
    int r = bx + yy, c = by + x;
    if (r < Cc && c < R) out[(long long)r * R + c] = t[x][yy];
  }
}

// ---------------- fused PPEG (16x128 strip, register column window) --------
__global__ __launch_bounds__(256) void ppeg_k(
    const float* __restrict__ cf, float* __restrict__ yt,
    const float* __restrict__ w7, const float* __restrict__ b7,
    const float* __restrict__ w5, const float* __restrict__ b5,
    const float* __restrict__ w3, const float* __restrict__ b3)
{
  __shared__ float tile[22][136];   // rows ys-3..ys+18, cols -3..130
  __shared__ float wsh[84];
  int c = blockIdx.y;
  int ys = blockIdx.x * 16;
  int tid = threadIdx.x;
  const float* img = cf + (long long)c * 16384;
  if (tid < 49) wsh[tid] = w7[c * 49 + tid];
  else if (tid >= 64 && tid < 89) wsh[49 + tid - 64] = w5[c * 25 + (tid - 64)];
  else if (tid >= 96 && tid < 105) wsh[74 + tid - 96] = w3[c * 9 + (tid - 96)];
  else if (tid == 128) wsh[83] = b7[c] + b5[c] + b3[c];
  for (int i = tid; i < 22 * 134; i += 256){
    int yy = i / 134, xx = i - yy * 134;
    int gy = ys - 3 + yy, gx = xx - 3;
    tile[yy][xx] = (gy >= 0 && gy < 128 && gx >= 0 && gx < 128) ? img[gy * 128 + gx] : 0.f;
  }
  __syncthreads();
  int x = tid & 127;
  int yo = (tid >> 7) * 8;     // 0 or 8
  float acc[8];
#pragma unroll
  for (int i = 0; i < 8; i++) acc[i] = tile[yo + i + 3][x + 3] + wsh[83];
#pragma unroll
  for (int kx = 0; kx < 7; kx++){
    float col[14];
#pragma unroll
    for (int t = 0; t < 14; t++) col[t] = tile[yo + t][x + kx];
    float wc7[7];
#pragma unroll
    for (int ky = 0; ky < 7; ky++) wc7[ky] = wsh[ky * 7 + kx];
#pragma unroll
    for (int i = 0; i < 8; i++)
#pragma unroll
      for (int ky = 0; ky < 7; ky++)
        acc[i] = fmaf(col[i + ky], wc7[ky], acc[i]);
    if (kx >= 1 && kx <= 5){
      float wc5[5];
#pragma unroll
      for (int ky = 0; ky < 5; ky++) wc5[ky] = wsh[49 + ky * 5 + (kx - 1)];
#pragma unroll
      for (int i = 0; i < 8; i++)
#pragma unroll
        for (int ky = 0; ky < 5; ky++)
          acc[i] = fmaf(col[i + 1 + ky], wc5[ky], acc[i]);
    }
    if (kx >= 2 && kx <= 4){
      float wc3[3];
#pragma unroll
      for (int ky = 0; ky < 3; ky++) wc3[ky] = wsh[74 + ky * 3 + (kx - 2)];
#pragma unroll
      for (int i = 0; i < 8; i++)
#pragma unroll
        for (int ky = 0; ky < 3; ky++)
          acc[i] = fmaf(col[i + 2 + ky], wc3[ky], acc[i]);
    }
  }
  float* dst = yt + (long long)c * 16384 + (ys + yo) * 128 + x;
#pragma unroll
  for (int i = 0; i < 8; i++) dst[i * 128] = acc[i];
}

// ---------------- final: LN(h[0]) @ fc2 + b ----------------
__global__ __launch_bounds__(256) void final_k(
    const float* __restrict__ h, const float* __restrict__ g,
    const float* __restrict__ b, const float* __restrict__ w,
    const float* __restrict__ bias, float* __restrict__ out)
{
  __shared__ float sm[4];
  __shared__ float pj[256][4];
  int tid = threadIdx.x;
  float v0 = h[tid], v1 = h[tid + 256];
  float s = bredSum(v0 + v1, sm);
  float s2 = bredSum(v0 * v0 + v1 * v1, sm);
  float mean = s * (1.f / 512.f);
  float var = s2 * (1.f / 512.f) - mean * mean;
  float rstd = rsqrtf(var + 1e-5f);
  float n0 = (v0 - mean) * rstd * g[tid] + b[tid];
  float n1 = (v1 - mean) * rstd * g[tid + 256] + b[tid + 256];
#pragma unroll
  for (int j = 0; j < 4; j++)
    pj[tid][j] = n0 * w[tid * 4 + j] + n1 * w[(tid + 256) * 4 + j];
  __syncthreads();
  if (tid < 4){
    float acc = 0.f;
    for (int k = 0; k < 256; k++) acc += pj[k][tid];
    out[tid] = acc + bias[tid];
  }
}

// ===========================================================================
// host side
// ===========================================================================
static inline void gemmbf(hipStream_t st, const u16* A, const u16* B, void* C,
                          int M, int N, int K, int lda, int ldb, int ldc,
                          long long sA, long long sB, long long sC, int batch,
                          const float* bias, const float* rowdiv, int sRow,
                          float alpha, int flags, int ksplit, u16* vt, int dbuf)
{
  dim3 grid((N + 127) / 128, (M + 127) / 128, batch * ksplit);
  if (dbuf)
    gemmbf_k<1><<<grid, 256, 0, st>>>(A, B, C, M, N, K, lda, ldb, ldc, sA, sB, sC,
                                      bias, rowdiv, sRow, alpha, flags, ksplit, vt);
  else
    gemmbf_k<0><<<grid, 256, 0, st>>>(A, B, C, M, N, K, lda, ldb, ldc, sA, sB, sC,
                                      bias, rowdiv, sRow, alpha, flags, ksplit, vt);
}

// workspace byte offsets
#define B_H     0LL
#define B_XQ    33556480LL     /* xq; after qkv, hosts pinv hi/lo arrays (16MB) */
#define B_ATTN  50595840LL
#define B_QKV   67635200LL     /* also xb; also cf/yt for PPEG */
#define B_VT    118753280LL
#define B_O3    135792640LL
#define B_ML3   142608384LL
#define B_QL    169871360LL
#define B_KL    170395648LL
#define B_QLH   170919936LL
#define B_KLH   171182080LL
#define B_A2    171444224LL
#define B_PV2   173541376LL    /* zah(1M), zal(1M), zf f32(2M) */
#define B_A3V   184027136LL
#define B_Z2    184551424LL
#define B_Z2T   185075712LL
#define B_SCAL  185604096LL
#define B_W1T   185604352LL
#define B_WQT   186652928LL
#define B_WOT   188225792LL
#define WS_REQ  188750080LL
#define MB1     1048576LL

extern "C" void kernel_launch(void* const* d_in, const int* in_sizes, int n_in,
                              void* d_out, int out_size, void* d_ws, size_t ws_size,
                              hipStream_t stream)
{
  (void)in_sizes; (void)n_in; (void)out_size;
  if (ws_size < (size_t)WS_REQ) return;

  const float* x      = (const float*)d_in[0];
  const float* fc1_w  = (const float*)d_in[1];
  const float* fc1_b  = (const float*)d_in[2];
  const float* cls    = (const float*)d_in[3];
  const float* l_ng[2]  = {(const float*)d_in[4],  (const float*)d_in[10]};
  const float* l_nb[2]  = {(const float*)d_in[5],  (const float*)d_in[11]};
  const float* l_qkv[2] = {(const float*)d_in[6],  (const float*)d_in[12]};
  const float* l_ow[2]  = {(const float*)d_in[7],  (const float*)d_in[13]};
  const float* l_ob[2]  = {(const float*)d_in[8],  (const float*)d_in[14]};
  const float* l_rw[2]  = {(const float*)d_in[9],  (const float*)d_in[15]};
  const float* w7 = (const float*)d_in[16];
  const float* b7 = (const float*)d_in[17];
  const float* w5 = (const float*)d_in[18];
  const float* b5 = (const float*)d_in[19];
  const float* w3 = (const float*)d_in[20];
  const float* b3 = (const float*)d_in[21];
  const float* norm_g = (const float*)d_in[22];
  const float* norm_b = (const float*)d_in[23];
  const float* fc2_w  = (const float*)d_in[24];
  const float* fc2_b  = (const float*)d_in[25];
  float* out = (float*)d_out;

  char* WB = (char*)d_ws;
  float* h    = (float*)(WB + B_H);
  u16*   xq   = (u16*)(WB + B_XQ);
  u16*   attnb= (u16*)(WB + B_ATTN);
  u16*   qkvb = (u16*)(WB + B_QKV);
  u16*   xb   = (u16*)(WB + B_QKV);
  float* cf   = (float*)(WB + B_QKV);
  float* yt   = (float*)(WB + B_QKV + 33554432LL);
  u16*   vT   = (u16*)(WB + B_VT);
  float* O3   = (float*)(WB + B_O3);
  float* ML3  = (float*)(WB + B_ML3);
  float* ql   = (float*)(WB + B_QL);
  float* kl   = (float*)(WB + B_KL);
  u16*   qlh  = (u16*)(WB + B_QLH);
  u16*   klh  = (u16*)(WB + B_KLH);
  float* a2   = (float*)(WB + B_A2);
  float* a3v  = (float*)(WB + B_A3V);
  float* Z2   = (float*)(WB + B_Z2);
  u16*   Z2T  = (u16*)(WB + B_Z2T);
  float* scal = (float*)(WB + B_SCAL);
  u16*   w1T  = (u16*)(WB + B_W1T);
  u16*   wqT  = (u16*)(WB + B_WQT);
  u16*   woT  = (u16*)(WB + B_WOT);

  u16* a2h  = (u16*)(WB + B_XQ + 0 * MB1);
  u16* a2l  = (u16*)(WB + B_XQ + 1 * MB1);
  u16* z0h  = (u16*)(WB + B_XQ + 2 * MB1);
  u16* z0l  = (u16*)(WB + B_XQ + 3 * MB1);
  u16* z0Th = (u16*)(WB + B_XQ + 4 * MB1);
  u16* z0Tl = (u16*)(WB + B_XQ + 5 * MB1);
  u16* z1h  = (u16*)(WB + B_XQ + 6 * MB1);
  u16* z1l  = (u16*)(WB + B_XQ + 7 * MB1);
  u16* z1Th = (u16*)(WB + B_XQ + 8 * MB1);
  u16* z1Tl = (u16*)(WB + B_XQ + 9 * MB1);
  u16* azh  = (u16*)(WB + B_XQ + 10 * MB1);
  u16* azl  = (u16*)(WB + B_XQ + 11 * MB1);
  u16* azTh = (u16*)(WB + B_XQ + 12 * MB1);
  u16* azTl = (u16*)(WB + B_XQ + 13 * MB1);
  u16* tATh = (u16*)(WB + B_XQ + 14 * MB1);
  u16* tATl = (u16*)(WB + B_XQ + 15 * MB1);
  u16* zah  = (u16*)(WB + B_PV2 + 0 * MB1);
  u16* zal  = (u16*)(WB + B_PV2 + 1 * MB1);
  float* zf = (float*)(WB + B_PV2 + 2 * MB1);

  // ---- fc1 ----
  copy_cls_k<<<1, 256, 0, stream>>>(cls, h);
  cvtbf_k<<<4096, 256, 0, stream>>>(x, xb, 16384LL * 1024);
  tcbf_k<<<dim3(16, 32, 1), 256, 0, stream>>>(fc1_w, w1T, 1024, 512, 512, 1024, 0, 0);
  gemmbf(stream, xb, w1T, h + CDIM, 16384, 512, 1024, 1024, 1024, 512,
         0, 0, 0, 1, fc1_b, nullptr, 0, 1.f, GB_RELU, 1, nullptr, 1);

  for (int L = 0; L < 2; L++){
    ln_pad_k<<<NP, 256, 0, stream>>>(h, l_ng[L], l_nb[L], xq);
    tcbf_k<<<dim3(48, 16, 1), 256, 0, stream>>>(l_qkv[L], wqT, 512, 1536, 1536, 512, 0, 0);
    // qkv: bf16 out, q pre-scaled 0.125, v emitted transposed only (vT)
    gemmbf(stream, xq, wqT, qkvb, NP, 1536, 512, 512, 512, 1536,
           0, 0, 0, 1, nullptr, nullptr, 0, 1.f, GB_STOREBF | GB_QSCALE | GB_SWZ, 1, vT, 1);
    landmark_k<<<LM / 2, 256, 0, stream>>>(qkvb, ql, kl, qlh, klh);
    // a2 = softmax(ql @ kl^T): f32 + hi/lo
    gemm_k<<<dim3(4, 4, 8), 256, 0, stream>>>(ql, kl, a2, LM, LM, DH, DH, DH, LM,
                                              16384, 16384, 65536, 1.f, GF_TRANSB);
    softmax256_k<<<dim3(LM, HEADS), 256, 0, stream>>>(a2, a2h, a2l, scal);
    // pinv init
    pinv_scal_k<<<HEADS, 256, 0, stream>>>(a2, scal);
    z0_k<<<dim3(LM, HEADS), 256, 0, stream>>>(a2, scal, z0h, z0l, z0Th, z0Tl);
    // 6 Newton-Schulz iterations, hi/lo bf16 MFMA, 3 chained GEMMs each
    u16 *zh = z0h, *zl = z0l, *zTh = z0Th, *zTl = z0Tl;
    u16 *nzh = z1h, *nzl = z1l, *nzTh = z1Th, *nzTl = z1Tl;
    dim3 pg(4, 4, HEADS), pg2(4, 4, 2 * HEADS);
    for (int it = 0; it < 6; it++){
      pinvh_k<<<pg, 256, 0, stream>>>(a2h, a2l, zTh, zTl,
                                      azh, azl, azTh, azTl, nullptr,
                                      nullptr, nullptr, 0.f, 1.f, 0.f);
      pinv2_k<<<pg2, 256, 0, stream>>>(azh, azl, azTh, azTl, zh, zl,
                                       tATh, tATl, zah, zal);
      pinvh_k<<<pg, 256, 0, stream>>>(zah, zal, tATh, tATl,
                                      nzh, nzl, nzTh, nzTl,
                                      (it == 5) ? zf : nullptr,
                                      zh, zl, 0.f, -0.25f, 3.25f);
      u16* t;
      t = zh; zh = nzh; nzh = t;   t = zl; zl = nzl; nzl = t;
      t = zTh; zTh = nzTh; nzTh = t; t = zTl; zTl = nzTl; nzTl = t;
    }
    // ---- S3 flash: partials over 13 key chunks, then combine -> a3v ----
    fattn_k<<<dim3(4, 13, 8), 256, 0, stream>>>(
        qlh, 64, qkvb + 512, 1536, vT, NP,
        16384, 64, 64LL * NP, 1280,
        nullptr, 0, O3, ML3, 13, 256, 1);
    comb3_k<<<dim3(64, 8), 256, 0, stream>>>(O3, ML3, a3v);
    // Z2 = pinv(a2) @ a3v (zf f32), then Z2T bf16 per head
    gemm_k<<<dim3(1, 4, 8), 256, 0, stream>>>(zf, a3v, Z2, LM, DH, LM, LM, DH, DH,
                                              65536, 16384, 16384, 1.f, 0);
    tcbf_k<<<dim3(2, 8, 8), 256, 0, stream>>>(Z2, Z2T, 256, 64, 64, 256, 16384, 16384);
    // ---- S1 flash: attn = softmax(q @ kl^T) @ Z2, exact (256 keys) ----
    fattn_k<<<dim3(260, 1, 8), 256, 0, stream>>>(
        qkvb, 1536, klh, 64, Z2T, 256,
        64, 16384, 16384, 256,
        attnb, CDIM, nullptr, nullptr, 1, NP, 0);
    // attn += depthwise 33-tap conv of v (reads contiguous vT rows)
    resconv_k<<<dim3(2, NP / 8), 256, 0, stream>>>(vT, l_rw[L], attnb);
    // h += attn[-NT:] @ out_w + out_b
    tcbf_k<<<dim3(16, 16, 1), 256, 0, stream>>>(l_ow[L], woT, 512, 512, 512, 512, 0, 0);
    gemmbf(stream, attnb + (long long)PAD * CDIM, woT, h, NT, CDIM, CDIM,
           CDIM, CDIM, CDIM, 0, 0, 0, 1, l_ob[L], nullptr, 0, 1.f, GB_ACCUM, 1, nullptr, 1);

    if (L == 0){
      transpose_k<<<dim3(16, 512), 256, 0, stream>>>(h + CDIM, cf, 16384, CDIM);
      ppeg_k<<<dim3(8, 512), 256, 0, stream>>>(cf, yt, w7, b7, w5, b5, w3, b3);
      transpose_k<<<dim3(512, 16), 256, 0, stream>>>(yt, h + CDIM, CDIM, 16384);
    }
  }

  final_k<<<1, 256, 0, stream>>>(h, norm_g, norm_b, fc2_w, fc2_b, out);
}